// Round 6
// baseline (620.177 us; speedup 1.0000x reference)
//
#include <hip/hip_runtime.h>
#include <stdint.h>

#define B_ 16
#define A_ 256
#define N_ 64
#define F_ 128
#define G_ 25
#define GP 32           // G padded to MFMA K=32
#define L_ 3
#define P_ (B_*A_)      // 4096 atoms
#define CUTOFF_ 5.0f
#define OFF0_ 1.2f

typedef float f32x4 __attribute__((ext_vector_type(4)));
typedef __bf16 bf16x8 __attribute__((ext_vector_type(8)));

__device__ __forceinline__ uint16_t f2bf(float f) {
    union { __bf16 b; uint16_t u; } v; v.b = (__bf16)f;  // RNE hw cvt
    return v.u;
}
// shifted softplus: log(1+e^x) - ln2, stable form
__device__ __forceinline__ float sspf(float x) {
    float t = __expf(-fabsf(x));
    return fmaxf(x, 0.0f) + __logf(1.0f + t) - 0.69314718055994531f;
}

// ---- prep: transpose+pad filter weights to bf16 ----
// w1t[l][f][k] (k<32, zero-padded), w2t[l][f][k]
__global__ void k_prepw(const float* __restrict__ fw1, const float* __restrict__ fw2,
                        uint16_t* __restrict__ w1t, uint16_t* __restrict__ w2t) {
    int t = blockIdx.x * 256 + threadIdx.x;
    if (t < L_ * F_ * GP) {
        int k = t & (GP - 1); int f = (t >> 5) & (F_ - 1); int l = t >> 12;
        float v = (k < G_) ? fw1[(l * G_ + k) * F_ + f] : 0.0f;
        w1t[t] = f2bf(v);
    }
    if (t < L_ * F_ * F_) {
        int k = t & (F_ - 1); int f = (t >> 7) & (F_ - 1); int l = t >> 14;
        w2t[t] = f2bf(fw2[(l * F_ + k) * F_ + f]);
    }
}

// ---- embedding gather ----
__global__ void k_embed(const float* __restrict__ emb, const int* __restrict__ Z,
                        float* __restrict__ x) {
    int t = blockIdx.x * 256 + threadIdx.x;   // P_*F_ threads
    int p = t >> 7, f = t & 127;
    x[t] = emb[Z[p] * F_ + f];
}

// ---- fp32 GEMM: y[4096,128] = x[4096,128] @ w[128,128] (bias-free) ----
__global__ __launch_bounds__(256) void k_proj(const float* __restrict__ xin,
                                              const float* __restrict__ w,
                                              float* __restrict__ yout) {
    __shared__ float xs[16][128];
    int rb = blockIdx.x * 16;
    int t = threadIdx.x;
#pragma unroll
    for (int i = 0; i < 8; ++i) {
        int idx = i * 256 + t;
        xs[idx >> 7][idx & 127] = xin[rb * 128 + idx];
    }
    __syncthreads();
    int c = t & 127;
    int rg = (t >> 7) * 8;
    float acc[8] = {0, 0, 0, 0, 0, 0, 0, 0};
    for (int k = 0; k < 128; ++k) {
        float wv = w[k * 128 + c];
#pragma unroll
        for (int i = 0; i < 8; ++i) acc[i] += xs[rg + i][k] * wv;
    }
#pragma unroll
    for (int i = 0; i < 8; ++i) yout[(rb + rg + i) * 128 + c] = acc[i];
}

// ---- fused per-atom layer kernel (MFMA), wave-per-atom, barrier-free ----
// WG = 256 thr = 4 waves = 4 atoms. Wave loops over 4 edge-tiles of 16:
// RBF -> H1=ssp(f@W1+b1) -> (per-wave LDS) -> W=(H1@W2+b2)*fcut ->
// pacc[f] += sum_e W[e][f]*y[nbr(e)][f]; single shuffle-reduce at end.
__global__ __launch_bounds__(256, 4) void k_layer(
        const float* __restrict__ pos, const int* __restrict__ nbr,
        const float* __restrict__ mask, const float* __restrict__ y,
        const uint16_t* __restrict__ w1t, const float* __restrict__ b1,
        const uint16_t* __restrict__ w2t, const float* __restrict__ b2,
        float* __restrict__ agg)
{
    __shared__ uint16_t h1[4][16 * 128];   // per-wave swizzled H1 tile (4 KiB each)
    const int wave = threadIdx.x >> 6;
    const int lane = threadIdx.x & 63;
    const int row  = lane & 15;            // A-row lane index (edge within tile)
    const int kg   = lane >> 4;            // k-group
    const int atom = blockIdx.x * 4 + wave;
    const int molbase = atom & ~(A_ - 1);

    const float px = pos[atom * 3 + 0];
    const float py = pos[atom * 3 + 1];
    const float pz = pos[atom * 3 + 2];

    // hoisted biases (constant across tiles)
    float b1v[8], b2v[8];
#pragma unroll
    for (int nt = 0; nt < 8; ++nt) {
        b1v[nt] = b1[nt * 16 + row];
        b2v[nt] = b2[nt * 16 + row];
    }

    const f32x4 zero = {0.0f, 0.0f, 0.0f, 0.0f};
    uint16_t* hl = h1[wave];
    const float step = 3.8f / 24.0f;
    const float coef = -0.5f / (step * step);

    float pacc[8] = {0.f, 0.f, 0.f, 0.f, 0.f, 0.f, 0.f, 0.f};

#pragma unroll 1
    for (int tile = 0; tile < 4; ++tile) {
        // --- RBF for this lane's edge (edge = tile*16+row; dup across kg) ---
        const int e_mine = atom * N_ + tile * 16 + row;
        const int jrow_mine = molbase + nbr[e_mine];
        const float dx = pos[jrow_mine * 3 + 0] - px;
        const float dy = pos[jrow_mine * 3 + 1] - py;
        const float dz = pos[jrow_mine * 3 + 2] - pz;
        const float r = sqrtf(dx * dx + dy * dy + dz * dz + 1e-9f);
        const float fcr = (r <= CUTOFF_) ? mask[e_mine] : 0.0f;
        union { bf16x8 v; uint16_t u[8]; } a1;
#pragma unroll
        for (int j = 0; j < 8; ++j) {
            const int k = kg * 8 + j;
            float val = 0.0f;
            if (k < G_) { const float d = r - (OFF0_ + step * (float)k); val = __expf(coef * d * d); }
            a1.u[j] = f2bf(val);
        }

        // GEMM1: [16,32]@[32,128], ssp epilogue -> XOR-swizzled per-wave LDS
#pragma unroll
        for (int nt = 0; nt < 8; ++nt) {
            bf16x8 bfr = *(const bf16x8*)(w1t + (nt * 16 + row) * GP + kg * 8);
            f32x4 acc1 = __builtin_amdgcn_mfma_f32_16x16x32_bf16(a1.v, bfr, zero, 0, 0, 0);
            const int col = nt * 16 + row;
#pragma unroll
            for (int j = 0; j < 4; ++j) {
                const int rr = kg * 4 + j;                     // D-row = edge in tile
                const int byt = rr * 256 + ((col * 2) ^ ((rr & 7) << 4));
                *(uint16_t*)((char*)hl + byt) = f2bf(sspf(acc1[j] + b1v[nt]));
            }
        }
        // (same-wave LDS write->read; compiler inserts lgkmcnt waits)

        // GEMM2: [16,128]@[128,128], K=128 in 4 steps
        f32x4 acc2[8];
#pragma unroll
        for (int nt = 0; nt < 8; ++nt) acc2[nt] = zero;
#pragma unroll
        for (int ks = 0; ks < 4; ++ks) {
            const int kbyte = ks * 64 + kg * 16;
            bf16x8 a2 = *(const bf16x8*)((char*)hl + row * 256 + (kbyte ^ ((row & 7) << 4)));
#pragma unroll
            for (int nt = 0; nt < 8; ++nt) {
                bf16x8 bfr = *(const bf16x8*)(w2t + (nt * 16 + row) * F_ + ks * 32 + kg * 8);
                acc2[nt] = __builtin_amdgcn_mfma_f32_16x16x32_bf16(a2, bfr, acc2[nt], 0, 0, 0);
            }
        }

        // fused epilogue: W = (acc2+b2)*fcut, modulate by gathered y, accumulate
        float fc[4]; int jr[4];
#pragma unroll
        for (int j = 0; j < 4; ++j) {
            fc[j] = __shfl(fcr, kg * 4 + j);          // fcut of edge kg*4+j
            jr[j] = __shfl(jrow_mine, kg * 4 + j);    // neighbor row of edge kg*4+j
        }
#pragma unroll
        for (int nt = 0; nt < 8; ++nt) {
            const int col = nt * 16 + row;
            float s = pacc[nt];
#pragma unroll
            for (int j = 0; j < 4; ++j) {
                const float wv = (acc2[nt][j] + b2v[nt]) * fc[j];
                s += wv * y[(size_t)jr[j] * F_ + col];
            }
            pacc[nt] = s;
        }
    }

    // single cross-kg reduce + direct global write
#pragma unroll
    for (int nt = 0; nt < 8; ++nt) {
        float s = pacc[nt];
        s += __shfl_xor(s, 16);
        s += __shfl_xor(s, 32);
        pacc[nt] = s;
    }
    if (kg == 0) {
#pragma unroll
        for (int nt = 0; nt < 8; ++nt)
            agg[(size_t)atom * F_ + nt * 16 + row] = pacc[nt];
    }
}

// ---- atom MLP: x += ssp(agg@wa + ba) @ wb + bb ----
__global__ __launch_bounds__(256) void k_out_mlp(
        const float* __restrict__ agg,
        const float* __restrict__ wa, const float* __restrict__ ba,
        const float* __restrict__ wb, const float* __restrict__ bb,
        float* __restrict__ x)
{
    __shared__ float s0[16][128];
    __shared__ float s1[16][128];
    int rb = blockIdx.x * 16;
    int t = threadIdx.x;
#pragma unroll
    for (int i = 0; i < 8; ++i) {
        int idx = i * 256 + t;
        s0[idx >> 7][idx & 127] = agg[rb * 128 + idx];
    }
    __syncthreads();
    int c = t & 127;
    int rg = (t >> 7) * 8;
    float acc[8] = {0, 0, 0, 0, 0, 0, 0, 0};
    for (int k = 0; k < 128; ++k) {
        float wv = wa[k * 128 + c];
#pragma unroll
        for (int i = 0; i < 8; ++i) acc[i] += s0[rg + i][k] * wv;
    }
    float bva = ba[c];
#pragma unroll
    for (int i = 0; i < 8; ++i) s1[rg + i][c] = sspf(acc[i] + bva);
    __syncthreads();
    float acc2[8] = {0, 0, 0, 0, 0, 0, 0, 0};
    for (int k = 0; k < 128; ++k) {
        float wv = wb[k * 128 + c];
#pragma unroll
        for (int i = 0; i < 8; ++i) acc2[i] += s1[rg + i][k] * wv;
    }
    float bvb = bb[c];
#pragma unroll
    for (int i = 0; i < 8; ++i) x[(rb + rg + i) * 128 + c] += acc2[i] + bvb;
}

// ---- final copy fp32 -> fp32 d_out (reference output dtype is float32) ----
__global__ void k_copy_out(const float* __restrict__ x, float* __restrict__ out) {
    int t = blockIdx.x * 256 + threadIdx.x;
    out[t] = x[t];
}

extern "C" void kernel_launch(void* const* d_in, const int* in_sizes, int n_in,
                              void* d_out, int out_size, void* d_ws, size_t ws_size,
                              hipStream_t stream) {
    const float* emb   = (const float*)d_in[0];
    const float* pos   = (const float*)d_in[1];
    const float* fw1   = (const float*)d_in[2];
    const float* fb1   = (const float*)d_in[3];
    const float* fw2   = (const float*)d_in[4];
    const float* fb2   = (const float*)d_in[5];
    const float* in2f  = (const float*)d_in[6];
    const float* f2o_w = (const float*)d_in[7];
    const float* f2o_b = (const float*)d_in[8];
    const float* dns_w = (const float*)d_in[9];
    const float* dns_b = (const float*)d_in[10];
    const int*   Z     = (const int*)d_in[11];
    const int*   nbrs  = (const int*)d_in[12];
    const float* mask  = (const float*)d_in[13];

    char* ws = (char*)d_ws;
    size_t off = 0;
    auto alloc = [&](size_t bytes) {
        char* p = ws + off; off += (bytes + 255) & ~(size_t)255; return p;
    };
    float*    x   = (float*)   alloc((size_t)P_ * F_ * 4);
    float*    y   = (float*)   alloc((size_t)P_ * F_ * 4);
    float*    agg = (float*)   alloc((size_t)P_ * F_ * 4);
    uint16_t* w1t = (uint16_t*)alloc((size_t)L_ * F_ * GP * 2);
    uint16_t* w2t = (uint16_t*)alloc((size_t)L_ * F_ * F_ * 2);
    // total scratch: ~6.4 MB

    k_prepw<<<192, 256, 0, stream>>>(fw1, fw2, w1t, w2t);
    k_embed<<<(P_ * F_) / 256, 256, 0, stream>>>(emb, Z, x);

    for (int l = 0; l < L_; ++l) {
        k_proj<<<P_ / 16, 256, 0, stream>>>(x, in2f + (size_t)l * F_ * F_, y);
        k_layer<<<P_ / 4, 256, 0, stream>>>(pos, nbrs, mask, y,
                                            w1t + (size_t)l * F_ * GP, fb1 + (size_t)l * F_,
                                            w2t + (size_t)l * F_ * F_, fb2 + (size_t)l * F_,
                                            agg);
        k_out_mlp<<<P_ / 16, 256, 0, stream>>>(agg,
                                               f2o_w + (size_t)l * F_ * F_, f2o_b + (size_t)l * F_,
                                               dns_w + (size_t)l * F_ * F_, dns_b + (size_t)l * F_,
                                               x);
    }
    k_copy_out<<<(P_ * F_) / 256, 256, 0, stream>>>(x, (float*)d_out);
}

// Round 7
// 559.612 us; speedup vs baseline: 1.1082x; 1.1082x over previous
//
#include <hip/hip_runtime.h>
#include <stdint.h>

#define B_ 16
#define A_ 256
#define N_ 64
#define F_ 128
#define G_ 25
#define GP 32           // G padded to MFMA K=32
#define L_ 3
#define P_ (B_*A_)      // 4096 atoms
#define CUTOFF_ 5.0f
#define OFF0_ 1.2f

typedef float f32x4 __attribute__((ext_vector_type(4)));
typedef __bf16 bf16x8 __attribute__((ext_vector_type(8)));

__device__ __forceinline__ uint16_t f2bf(float f) {
    union { __bf16 b; uint16_t u; } v; v.b = (__bf16)f;  // RNE hw cvt
    return v.u;
}
// shifted softplus: log(1+e^x) - ln2, stable form
__device__ __forceinline__ float sspf(float x) {
    float t = __expf(-fabsf(x));
    return fmaxf(x, 0.0f) + __logf(1.0f + t) - 0.69314718055994531f;
}

// ---- prep: transpose+pad filter weights to bf16 ----
// w1t[l][f][k] (k<32, zero-padded), w2t[l][f][k]
__global__ void k_prepw(const float* __restrict__ fw1, const float* __restrict__ fw2,
                        uint16_t* __restrict__ w1t, uint16_t* __restrict__ w2t) {
    int t = blockIdx.x * 256 + threadIdx.x;
    if (t < L_ * F_ * GP) {
        int k = t & (GP - 1); int f = (t >> 5) & (F_ - 1); int l = t >> 12;
        float v = (k < G_) ? fw1[(l * G_ + k) * F_ + f] : 0.0f;
        w1t[t] = f2bf(v);
    }
    if (t < L_ * F_ * F_) {
        int k = t & (F_ - 1); int f = (t >> 7) & (F_ - 1); int l = t >> 14;
        w2t[t] = f2bf(fw2[(l * F_ + k) * F_ + f]);
    }
}

// ---- embedding gather ----
__global__ void k_embed(const float* __restrict__ emb, const int* __restrict__ Z,
                        float* __restrict__ x) {
    int t = blockIdx.x * 256 + threadIdx.x;   // P_*F_ threads
    int p = t >> 7, f = t & 127;
    x[t] = emb[Z[p] * F_ + f];
}

// ---- fp32 GEMM: y[4096,128] = x[4096,128] @ w[128,128] (bias-free) ----
__global__ __launch_bounds__(256) void k_proj(const float* __restrict__ xin,
                                              const float* __restrict__ w,
                                              float* __restrict__ yout) {
    __shared__ float xs[16][128];
    int rb = blockIdx.x * 16;
    int t = threadIdx.x;
#pragma unroll
    for (int i = 0; i < 8; ++i) {
        int idx = i * 256 + t;
        xs[idx >> 7][idx & 127] = xin[rb * 128 + idx];
    }
    __syncthreads();
    int c = t & 127;
    int rg = (t >> 7) * 8;
    float acc[8] = {0, 0, 0, 0, 0, 0, 0, 0};
    for (int k = 0; k < 128; ++k) {
        float wv = w[k * 128 + c];
#pragma unroll
        for (int i = 0; i < 8; ++i) acc[i] += xs[rg + i][k] * wv;
    }
#pragma unroll
    for (int i = 0; i < 8; ++i) yout[(rb + rg + i) * 128 + c] = acc[i];
}

// ---- fused per-atom layer kernel (MFMA), wave-per-atom, LDS-staged weights ----
// WG = 512 thr = 8 waves = 8 atoms. One barrier (weight staging), then each
// wave loops over its atom's 4 edge-tiles of 16:
// RBF -> H1=ssp(f@W1+b1) -> (per-wave LDS) -> W=(H1@W2+b2)*fcut ->
// pacc[f] += sum_e W[e][f]*y[nbr(e)][f]; single shuffle-reduce at end.
__global__ __launch_bounds__(512, 4) void k_layer(
        const float* __restrict__ pos, const int* __restrict__ nbr,
        const float* __restrict__ mask, const float* __restrict__ y,
        const uint16_t* __restrict__ w1t, const float* __restrict__ b1,
        const uint16_t* __restrict__ w2t, const float* __restrict__ b2,
        float* __restrict__ agg)
{
    __shared__ uint16_t w1s[F_ * GP];      // 8 KB, swizzled: f*64B + (k2 ^ ((f&3)<<4))
    __shared__ uint16_t w2s[F_ * F_];      // 32 KB, swizzled: f*256B + (k2 ^ ((f&7)<<4))
    __shared__ uint16_t h1[8][16 * 128];   // per-wave swizzled H1 tile (4 KiB each)

    // ---- cooperative weight staging (coalesced 16B, swizzled LDS dst) ----
    {
        const int t = threadIdx.x;
        const int f1 = t >> 2, kc1 = (t & 3) * 8;           // w1: 128f x 32k, 512 vec8
        uint4 v1 = *(const uint4*)(w1t + f1 * GP + kc1);
        *(uint4*)((char*)w1s + f1 * 64 + ((kc1 * 2) ^ ((f1 & 3) << 4))) = v1;
#pragma unroll
        for (int i = 0; i < 4; ++i) {                        // w2: 128f x 128k, 2048 vec8
            const int idx = i * 512 + t;
            const int f2 = idx >> 4, kc2 = (idx & 15) * 8;
            uint4 v2 = *(const uint4*)(w2t + f2 * F_ + kc2);
            *(uint4*)((char*)w2s + f2 * 256 + ((kc2 * 2) ^ ((f2 & 7) << 4))) = v2;
        }
    }
    __syncthreads();

    const int wave = threadIdx.x >> 6;
    const int lane = threadIdx.x & 63;
    const int row  = lane & 15;            // A-row lane index (edge within tile)
    const int kg   = lane >> 4;            // k-group
    const int atom = blockIdx.x * 8 + wave;
    const int molbase = atom & ~(A_ - 1);

    const float px = pos[atom * 3 + 0];
    const float py = pos[atom * 3 + 1];
    const float pz = pos[atom * 3 + 2];

    // hoisted biases (constant across tiles)
    float b1v[8], b2v[8];
#pragma unroll
    for (int nt = 0; nt < 8; ++nt) {
        b1v[nt] = b1[nt * 16 + row];
        b2v[nt] = b2[nt * 16 + row];
    }

    const f32x4 zero = {0.0f, 0.0f, 0.0f, 0.0f};
    uint16_t* hl = h1[wave];
    const float step = 3.8f / 24.0f;
    const float coef = -0.5f / (step * step);

    float pacc[8] = {0.f, 0.f, 0.f, 0.f, 0.f, 0.f, 0.f, 0.f};

#pragma unroll 1
    for (int tile = 0; tile < 4; ++tile) {
        // --- RBF for this lane's edge (edge = tile*16+row; dup across kg) ---
        const int e_mine = atom * N_ + tile * 16 + row;
        const int jrow_mine = molbase + nbr[e_mine];
        const float dx = pos[jrow_mine * 3 + 0] - px;
        const float dy = pos[jrow_mine * 3 + 1] - py;
        const float dz = pos[jrow_mine * 3 + 2] - pz;
        const float r = sqrtf(dx * dx + dy * dy + dz * dz + 1e-9f);
        const float fcr = (r <= CUTOFF_) ? mask[e_mine] : 0.0f;
        union { bf16x8 v; uint16_t u[8]; } a1;
#pragma unroll
        for (int j = 0; j < 8; ++j) {
            const int k = kg * 8 + j;
            float val = 0.0f;
            if (k < G_) { const float d = r - (OFF0_ + step * (float)k); val = __expf(coef * d * d); }
            a1.u[j] = f2bf(val);
        }

        // GEMM1: [16,32]@[32,128], B from LDS, ssp epilogue -> swizzled h1
#pragma unroll
        for (int nt = 0; nt < 8; ++nt) {
            bf16x8 bfr = *(const bf16x8*)((char*)w1s + (nt * 16 + row) * 64 +
                                          ((kg * 16) ^ ((row & 3) << 4)));
            f32x4 acc1 = __builtin_amdgcn_mfma_f32_16x16x32_bf16(a1.v, bfr, zero, 0, 0, 0);
            const int col = nt * 16 + row;
#pragma unroll
            for (int j = 0; j < 4; ++j) {
                const int rr = kg * 4 + j;                     // D-row = edge in tile
                const int byt = rr * 256 + ((col * 2) ^ ((rr & 7) << 4));
                *(uint16_t*)((char*)hl + byt) = f2bf(sspf(acc1[j] + b1v[nt]));
            }
        }
        // (same-wave LDS write->read; compiler inserts lgkmcnt waits)

        // GEMM2: [16,128]@[128,128], K=128 in 4 steps, B from LDS
        f32x4 acc2[8];
#pragma unroll
        for (int nt = 0; nt < 8; ++nt) acc2[nt] = zero;
#pragma unroll
        for (int ks = 0; ks < 4; ++ks) {
            const int kbyte = ks * 64 + kg * 16;
            bf16x8 a2 = *(const bf16x8*)((char*)hl + row * 256 + (kbyte ^ ((row & 7) << 4)));
#pragma unroll
            for (int nt = 0; nt < 8; ++nt) {
                bf16x8 bfr = *(const bf16x8*)((char*)w2s + (nt * 16 + row) * 256 +
                                              (kbyte ^ ((row & 7) << 4)));
                acc2[nt] = __builtin_amdgcn_mfma_f32_16x16x32_bf16(a2, bfr, acc2[nt], 0, 0, 0);
            }
        }

        // fused epilogue: W = (acc2+b2)*fcut, modulate by gathered y, accumulate
        float fc[4]; int jr[4];
#pragma unroll
        for (int j = 0; j < 4; ++j) {
            fc[j] = __shfl(fcr, kg * 4 + j);          // fcut of edge kg*4+j
            jr[j] = __shfl(jrow_mine, kg * 4 + j);    // neighbor row of edge kg*4+j
        }
#pragma unroll
        for (int nt = 0; nt < 8; ++nt) {
            const int col = nt * 16 + row;
            float s = pacc[nt];
#pragma unroll
            for (int j = 0; j < 4; ++j) {
                const float wv = (acc2[nt][j] + b2v[nt]) * fc[j];
                s += wv * y[(size_t)jr[j] * F_ + col];
            }
            pacc[nt] = s;
        }
    }

    // single cross-kg reduce + direct global write
#pragma unroll
    for (int nt = 0; nt < 8; ++nt) {
        float s = pacc[nt];
        s += __shfl_xor(s, 16);
        s += __shfl_xor(s, 32);
        pacc[nt] = s;
    }
    if (kg == 0) {
#pragma unroll
        for (int nt = 0; nt < 8; ++nt)
            agg[(size_t)atom * F_ + nt * 16 + row] = pacc[nt];
    }
}

// ---- atom MLP: x += ssp(agg@wa + ba) @ wb + bb ----
__global__ __launch_bounds__(256) void k_out_mlp(
        const float* __restrict__ agg,
        const float* __restrict__ wa, const float* __restrict__ ba,
        const float* __restrict__ wb, const float* __restrict__ bb,
        float* __restrict__ x)
{
    __shared__ float s0[16][128];
    __shared__ float s1[16][128];
    int rb = blockIdx.x * 16;
    int t = threadIdx.x;
#pragma unroll
    for (int i = 0; i < 8; ++i) {
        int idx = i * 256 + t;
        s0[idx >> 7][idx & 127] = agg[rb * 128 + idx];
    }
    __syncthreads();
    int c = t & 127;
    int rg = (t >> 7) * 8;
    float acc[8] = {0, 0, 0, 0, 0, 0, 0, 0};
    for (int k = 0; k < 128; ++k) {
        float wv = wa[k * 128 + c];
#pragma unroll
        for (int i = 0; i < 8; ++i) acc[i] += s0[rg + i][k] * wv;
    }
    float bva = ba[c];
#pragma unroll
    for (int i = 0; i < 8; ++i) s1[rg + i][c] = sspf(acc[i] + bva);
    __syncthreads();
    float acc2[8] = {0, 0, 0, 0, 0, 0, 0, 0};
    for (int k = 0; k < 128; ++k) {
        float wv = wb[k * 128 + c];
#pragma unroll
        for (int i = 0; i < 8; ++i) acc2[i] += s1[rg + i][k] * wv;
    }
    float bvb = bb[c];
#pragma unroll
    for (int i = 0; i < 8; ++i) x[(rb + rg + i) * 128 + c] += acc2[i] + bvb;
}

// ---- final copy fp32 -> fp32 d_out (reference output dtype is float32) ----
__global__ void k_copy_out(const float* __restrict__ x, float* __restrict__ out) {
    int t = blockIdx.x * 256 + threadIdx.x;
    out[t] = x[t];
}

extern "C" void kernel_launch(void* const* d_in, const int* in_sizes, int n_in,
                              void* d_out, int out_size, void* d_ws, size_t ws_size,
                              hipStream_t stream) {
    const float* emb   = (const float*)d_in[0];
    const float* pos   = (const float*)d_in[1];
    const float* fw1   = (const float*)d_in[2];
    const float* fb1   = (const float*)d_in[3];
    const float* fw2   = (const float*)d_in[4];
    const float* fb2   = (const float*)d_in[5];
    const float* in2f  = (const float*)d_in[6];
    const float* f2o_w = (const float*)d_in[7];
    const float* f2o_b = (const float*)d_in[8];
    const float* dns_w = (const float*)d_in[9];
    const float* dns_b = (const float*)d_in[10];
    const int*   Z     = (const int*)d_in[11];
    const int*   nbrs  = (const int*)d_in[12];
    const float* mask  = (const float*)d_in[13];

    char* ws = (char*)d_ws;
    size_t off = 0;
    auto alloc = [&](size_t bytes) {
        char* p = ws + off; off += (bytes + 255) & ~(size_t)255; return p;
    };
    float*    x   = (float*)   alloc((size_t)P_ * F_ * 4);
    float*    y   = (float*)   alloc((size_t)P_ * F_ * 4);
    float*    agg = (float*)   alloc((size_t)P_ * F_ * 4);
    uint16_t* w1t = (uint16_t*)alloc((size_t)L_ * F_ * GP * 2);
    uint16_t* w2t = (uint16_t*)alloc((size_t)L_ * F_ * F_ * 2);
    // total scratch: ~6.4 MB

    k_prepw<<<192, 256, 0, stream>>>(fw1, fw2, w1t, w2t);
    k_embed<<<(P_ * F_) / 256, 256, 0, stream>>>(emb, Z, x);

    for (int l = 0; l < L_; ++l) {
        k_proj<<<P_ / 16, 256, 0, stream>>>(x, in2f + (size_t)l * F_ * F_, y);
        k_layer<<<P_ / 8, 512, 0, stream>>>(pos, nbrs, mask, y,
                                            w1t + (size_t)l * F_ * GP, fb1 + (size_t)l * F_,
                                            w2t + (size_t)l * F_ * F_, fb2 + (size_t)l * F_,
                                            agg);
        k_out_mlp<<<P_ / 16, 256, 0, stream>>>(agg,
                                               f2o_w + (size_t)l * F_ * F_, f2o_b + (size_t)l * F_,
                                               dns_w + (size_t)l * F_ * F_, dns_b + (size_t)l * F_,
                                               x);
    }
    k_copy_out<<<(P_ * F_) / 256, 256, 0, stream>>>(x, (float*)d_out);
}

// Round 8
// 555.164 us; speedup vs baseline: 1.1171x; 1.0080x over previous
//
#include <hip/hip_runtime.h>
#include <stdint.h>

#define B_ 16
#define A_ 256
#define N_ 64
#define F_ 128
#define G_ 25
#define GP 32           // G padded to MFMA K=32
#define L_ 3
#define P_ (B_*A_)      // 4096 atoms
#define CUTOFF_ 5.0f
#define OFF0_ 1.2f

typedef float f32x4 __attribute__((ext_vector_type(4)));
typedef __bf16 bf16x8 __attribute__((ext_vector_type(8)));

#define F8(OP) OP(0) OP(1) OP(2) OP(3) OP(4) OP(5) OP(6) OP(7)

__device__ __forceinline__ uint16_t f2bf(float f) {
    union { __bf16 b; uint16_t u; } v; v.b = (__bf16)f;  // RNE hw cvt
    return v.u;
}
// shifted softplus: log(1+e^x) - ln2, stable form
__device__ __forceinline__ float sspf(float x) {
    float t = __expf(-fabsf(x));
    return fmaxf(x, 0.0f) + __logf(1.0f + t) - 0.69314718055994531f;
}

// ---- prep: transpose+pad filter weights to bf16 ----
__global__ void k_prepw(const float* __restrict__ fw1, const float* __restrict__ fw2,
                        uint16_t* __restrict__ w1t, uint16_t* __restrict__ w2t) {
    int t = blockIdx.x * 256 + threadIdx.x;
    if (t < L_ * F_ * GP) {
        int k = t & (GP - 1); int f = (t >> 5) & (F_ - 1); int l = t >> 12;
        float v = (k < G_) ? fw1[(l * G_ + k) * F_ + f] : 0.0f;
        w1t[t] = f2bf(v);
    }
    if (t < L_ * F_ * F_) {
        int k = t & (F_ - 1); int f = (t >> 7) & (F_ - 1); int l = t >> 14;
        w2t[t] = f2bf(fw2[(l * F_ + k) * F_ + f]);
    }
}

// ---- embedding gather ----
__global__ void k_embed(const float* __restrict__ emb, const int* __restrict__ Z,
                        float* __restrict__ x) {
    int t = blockIdx.x * 256 + threadIdx.x;   // P_*F_ threads
    int p = t >> 7, f = t & 127;
    x[t] = emb[Z[p] * F_ + f];
}

// ---- fp32 GEMM: y[4096,128] = x[4096,128] @ w[128,128] (bias-free) ----
__global__ __launch_bounds__(256) void k_proj(const float* __restrict__ xin,
                                              const float* __restrict__ w,
                                              float* __restrict__ yout) {
    __shared__ float xs[16][128];
    int rb = blockIdx.x * 16;
    int t = threadIdx.x;
#pragma unroll
    for (int i = 0; i < 8; ++i) {
        int idx = i * 256 + t;
        xs[idx >> 7][idx & 127] = xin[rb * 128 + idx];
    }
    __syncthreads();
    int c = t & 127;
    int rg = (t >> 7) * 8;
    float acc[8] = {0, 0, 0, 0, 0, 0, 0, 0};
    for (int k = 0; k < 128; ++k) {
        float wv = w[k * 128 + c];
#pragma unroll
        for (int i = 0; i < 8; ++i) acc[i] += xs[rg + i][k] * wv;
    }
#pragma unroll
    for (int i = 0; i < 8; ++i) yout[(rb + rg + i) * 128 + c] = acc[i];
}

// ---- fused per-atom layer kernel (MFMA), wave-per-atom, LDS-staged weights ----
// WG = 512 thr = 8 waves = 8 atoms. One barrier (weight staging), then each
// wave loops over its atom's 4 edge-tiles of 16. All per-tile state in NAMED
// registers (no aggregates) to keep SROA from demoting to scratch.
__global__ __launch_bounds__(512, 4) void k_layer(
        const float* __restrict__ pos, const int* __restrict__ nbr,
        const float* __restrict__ mask, const float* __restrict__ y,
        const uint16_t* __restrict__ w1t, const float* __restrict__ b1,
        const uint16_t* __restrict__ w2t, const float* __restrict__ b2,
        float* __restrict__ agg)
{
    __shared__ uint16_t w1s[F_ * GP];      // 8 KB, swizzled: f*64B + (k2 ^ ((f&3)<<4))
    __shared__ uint16_t w2s[F_ * F_];      // 32 KB, swizzled: f*256B + (k2 ^ ((f&7)<<4))
    __shared__ uint16_t h1[8][16 * 128];   // per-wave swizzled H1 tile (4 KiB each)

    // ---- cooperative weight staging (coalesced 16B, swizzled LDS dst) ----
    {
        const int t = threadIdx.x;
        const int f1 = t >> 2, kc1 = (t & 3) * 8;           // w1: 128f x 32k, 512 vec8
        uint4 v1 = *(const uint4*)(w1t + f1 * GP + kc1);
        *(uint4*)((char*)w1s + f1 * 64 + ((kc1 * 2) ^ ((f1 & 3) << 4))) = v1;
#pragma unroll
        for (int i = 0; i < 4; ++i) {                        // w2: 128f x 128k, 2048 vec8
            const int idx = i * 512 + t;
            const int f2 = idx >> 4, kc2 = (idx & 15) * 8;
            uint4 v2 = *(const uint4*)(w2t + f2 * F_ + kc2);
            *(uint4*)((char*)w2s + f2 * 256 + ((kc2 * 2) ^ ((f2 & 7) << 4))) = v2;
        }
    }
    __syncthreads();

    const int wave = threadIdx.x >> 6;
    const int lane = threadIdx.x & 63;
    const int row  = lane & 15;            // A-row lane index (edge within tile)
    const int kg   = lane >> 4;            // k-group
    const int atom = blockIdx.x * 8 + wave;
    const int molbase = atom & ~(A_ - 1);

    const float px = pos[atom * 3 + 0];
    const float py = pos[atom * 3 + 1];
    const float pz = pos[atom * 3 + 2];

    // hoisted biases (named registers)
#define DECLB(nt) const float b1v_##nt = b1[(nt) * 16 + row]; \
                  const float b2v_##nt = b2[(nt) * 16 + row];
    F8(DECLB)
#undef DECLB

#define DECLP(nt) float pacc_##nt = 0.0f;
    F8(DECLP)
#undef DECLP

    const f32x4 zero = {0.0f, 0.0f, 0.0f, 0.0f};
    uint16_t* hl = h1[wave];
    const float step = 3.8f / 24.0f;
    const float coef = -0.5f / (step * step);

#pragma unroll 1
    for (int tile = 0; tile < 4; ++tile) {
        // --- RBF for this lane's edge (edge = tile*16+row; dup across kg) ---
        const int e_mine = atom * N_ + tile * 16 + row;
        const int jrow_mine = molbase + nbr[e_mine];
        const float dx = pos[jrow_mine * 3 + 0] - px;
        const float dy = pos[jrow_mine * 3 + 1] - py;
        const float dz = pos[jrow_mine * 3 + 2] - pz;
        const float r = sqrtf(dx * dx + dy * dy + dz * dz + 1e-9f);
        const float fcr = (r <= CUTOFF_) ? mask[e_mine] : 0.0f;
        bf16x8 a1v;
#pragma unroll
        for (int j = 0; j < 8; ++j) {
            const int k = kg * 8 + j;
            float val = 0.0f;
            if (k < G_) { const float d = r - (OFF0_ + step * (float)k); val = __expf(coef * d * d); }
            a1v[j] = (__bf16)val;
        }

        // GEMM1: [16,32]@[32,128], B from LDS, ssp epilogue -> swizzled h1
#define G1(nt) { \
            bf16x8 bfr = *(const bf16x8*)((char*)w1s + ((nt) * 16 + row) * 64 + \
                                          ((kg * 16) ^ ((row & 3) << 4))); \
            f32x4 acc1 = __builtin_amdgcn_mfma_f32_16x16x32_bf16(a1v, bfr, zero, 0, 0, 0); \
            const int col = (nt) * 16 + row; \
            _Pragma("unroll") \
            for (int j = 0; j < 4; ++j) { \
                const int rr = kg * 4 + j; \
                const int byt = rr * 256 + ((col * 2) ^ ((rr & 7) << 4)); \
                *(uint16_t*)((char*)hl + byt) = f2bf(sspf(acc1[j] + b1v_##nt)); \
            } }
        F8(G1)
#undef G1

        // GEMM2: [16,128]@[128,128], K=128 in 4 steps, B from LDS
#define DECLA(nt) f32x4 acc2_##nt = zero;
        F8(DECLA)
#undef DECLA
#pragma unroll
        for (int ks = 0; ks < 4; ++ks) {
            const int kbyte = ks * 64 + kg * 16;
            bf16x8 a2 = *(const bf16x8*)((char*)hl + row * 256 + (kbyte ^ ((row & 7) << 4)));
#define G2(nt) { \
                bf16x8 bfr = *(const bf16x8*)((char*)w2s + ((nt) * 16 + row) * 256 + \
                                              (kbyte ^ ((row & 7) << 4))); \
                acc2_##nt = __builtin_amdgcn_mfma_f32_16x16x32_bf16(a2, bfr, acc2_##nt, 0, 0, 0); }
            F8(G2)
#undef G2
        }

        // fused epilogue: W = (acc2+b2)*fcut, modulate by gathered y, accumulate
        const float fc0 = __shfl(fcr, kg * 4 + 0);
        const float fc1 = __shfl(fcr, kg * 4 + 1);
        const float fc2 = __shfl(fcr, kg * 4 + 2);
        const float fc3 = __shfl(fcr, kg * 4 + 3);
        const int jr0 = __shfl(jrow_mine, kg * 4 + 0);
        const int jr1 = __shfl(jrow_mine, kg * 4 + 1);
        const int jr2 = __shfl(jrow_mine, kg * 4 + 2);
        const int jr3 = __shfl(jrow_mine, kg * 4 + 3);
#define EPI(nt) { \
            const int col = (nt) * 16 + row; \
            float s = pacc_##nt; \
            s += (acc2_##nt[0] + b2v_##nt) * fc0 * y[(size_t)jr0 * F_ + col]; \
            s += (acc2_##nt[1] + b2v_##nt) * fc1 * y[(size_t)jr1 * F_ + col]; \
            s += (acc2_##nt[2] + b2v_##nt) * fc2 * y[(size_t)jr2 * F_ + col]; \
            s += (acc2_##nt[3] + b2v_##nt) * fc3 * y[(size_t)jr3 * F_ + col]; \
            pacc_##nt = s; }
        F8(EPI)
#undef EPI
    }

    // single cross-kg reduce + direct global write
#define RED(nt) { \
        float s = pacc_##nt; \
        s += __shfl_xor(s, 16); \
        s += __shfl_xor(s, 32); \
        if (kg == 0) agg[(size_t)atom * F_ + (nt) * 16 + row] = s; }
    F8(RED)
#undef RED
}

// ---- atom MLP: x += ssp(agg@wa + ba) @ wb + bb ----
__global__ __launch_bounds__(256) void k_out_mlp(
        const float* __restrict__ agg,
        const float* __restrict__ wa, const float* __restrict__ ba,
        const float* __restrict__ wb, const float* __restrict__ bb,
        float* __restrict__ x)
{
    __shared__ float s0[16][128];
    __shared__ float s1[16][128];
    int rb = blockIdx.x * 16;
    int t = threadIdx.x;
#pragma unroll
    for (int i = 0; i < 8; ++i) {
        int idx = i * 256 + t;
        s0[idx >> 7][idx & 127] = agg[rb * 128 + idx];
    }
    __syncthreads();
    int c = t & 127;
    int rg = (t >> 7) * 8;
    float acc[8] = {0, 0, 0, 0, 0, 0, 0, 0};
    for (int k = 0; k < 128; ++k) {
        float wv = wa[k * 128 + c];
#pragma unroll
        for (int i = 0; i < 8; ++i) acc[i] += s0[rg + i][k] * wv;
    }
    float bva = ba[c];
#pragma unroll
    for (int i = 0; i < 8; ++i) s1[rg + i][c] = sspf(acc[i] + bva);
    __syncthreads();
    float acc2[8] = {0, 0, 0, 0, 0, 0, 0, 0};
    for (int k = 0; k < 128; ++k) {
        float wv = wb[k * 128 + c];
#pragma unroll
        for (int i = 0; i < 8; ++i) acc2[i] += s1[rg + i][k] * wv;
    }
    float bvb = bb[c];
#pragma unroll
    for (int i = 0; i < 8; ++i) x[(rb + rg + i) * 128 + c] += acc2[i] + bvb;
}

// ---- final copy fp32 -> fp32 d_out (reference output dtype is float32) ----
__global__ void k_copy_out(const float* __restrict__ x, float* __restrict__ out) {
    int t = blockIdx.x * 256 + threadIdx.x;
    out[t] = x[t];
}

extern "C" void kernel_launch(void* const* d_in, const int* in_sizes, int n_in,
                              void* d_out, int out_size, void* d_ws, size_t ws_size,
                              hipStream_t stream) {
    const float* emb   = (const float*)d_in[0];
    const float* pos   = (const float*)d_in[1];
    const float* fw1   = (const float*)d_in[2];
    const float* fb1   = (const float*)d_in[3];
    const float* fw2   = (const float*)d_in[4];
    const float* fb2   = (const float*)d_in[5];
    const float* in2f  = (const float*)d_in[6];
    const float* f2o_w = (const float*)d_in[7];
    const float* f2o_b = (const float*)d_in[8];
    const float* dns_w = (const float*)d_in[9];
    const float* dns_b = (const float*)d_in[10];
    const int*   Z     = (const int*)d_in[11];
    const int*   nbrs  = (const int*)d_in[12];
    const float* mask  = (const float*)d_in[13];

    char* ws = (char*)d_ws;
    size_t off = 0;
    auto alloc = [&](size_t bytes) {
        char* p = ws + off; off += (bytes + 255) & ~(size_t)255; return p;
    };
    float*    x   = (float*)   alloc((size_t)P_ * F_ * 4);
    float*    y   = (float*)   alloc((size_t)P_ * F_ * 4);
    float*    agg = (float*)   alloc((size_t)P_ * F_ * 4);
    uint16_t* w1t = (uint16_t*)alloc((size_t)L_ * F_ * GP * 2);
    uint16_t* w2t = (uint16_t*)alloc((size_t)L_ * F_ * F_ * 2);
    // total scratch: ~6.4 MB

    k_prepw<<<192, 256, 0, stream>>>(fw1, fw2, w1t, w2t);
    k_embed<<<(P_ * F_) / 256, 256, 0, stream>>>(emb, Z, x);

    for (int l = 0; l < L_; ++l) {
        k_proj<<<P_ / 16, 256, 0, stream>>>(x, in2f + (size_t)l * F_ * F_, y);
        k_layer<<<P_ / 8, 512, 0, stream>>>(pos, nbrs, mask, y,
                                            w1t + (size_t)l * F_ * GP, fb1 + (size_t)l * F_,
                                            w2t + (size_t)l * F_ * F_, fb2 + (size_t)l * F_,
                                            agg);
        k_out_mlp<<<P_ / 16, 256, 0, stream>>>(agg,
                                               f2o_w + (size_t)l * F_ * F_, f2o_b + (size_t)l * F_,
                                               dns_w + (size_t)l * F_ * F_, dns_b + (size_t)l * F_,
                                               x);
    }
    k_copy_out<<<(P_ * F_) / 256, 256, 0, stream>>>(x, (float*)d_out);
}

// Round 9
// 391.017 us; speedup vs baseline: 1.5861x; 1.4198x over previous
//
#include <hip/hip_runtime.h>
#include <stdint.h>

#define B_ 16
#define A_ 256
#define N_ 64
#define F_ 128
#define G_ 25
#define GP 32           // G padded to MFMA K=32
#define L_ 3
#define P_ (B_*A_)      // 4096 atoms
#define CUTOFF_ 5.0f
#define OFF0_ 1.2f

typedef float f32x4 __attribute__((ext_vector_type(4)));
typedef __bf16 bf16x8 __attribute__((ext_vector_type(8)));

__device__ __forceinline__ uint16_t f2bf(float f) {
    union { __bf16 b; uint16_t u; } v; v.b = (__bf16)f;  // RNE hw cvt
    return v.u;
}
// shifted softplus: log(1+e^x) - ln2, stable form
__device__ __forceinline__ float sspf(float x) {
    float t = __expf(-fabsf(x));
    return fmaxf(x, 0.0f) + __logf(1.0f + t) - 0.69314718055994531f;
}

// ---- prep: transpose+pad filter weights to bf16 ----
__global__ void k_prepw(const float* __restrict__ fw1, const float* __restrict__ fw2,
                        uint16_t* __restrict__ w1t, uint16_t* __restrict__ w2t) {
    int t = blockIdx.x * 256 + threadIdx.x;
    if (t < L_ * F_ * GP) {
        int k = t & (GP - 1); int f = (t >> 5) & (F_ - 1); int l = t >> 12;
        float v = (k < G_) ? fw1[(l * G_ + k) * F_ + f] : 0.0f;
        w1t[t] = f2bf(v);
    }
    if (t < L_ * F_ * F_) {
        int k = t & (F_ - 1); int f = (t >> 7) & (F_ - 1); int l = t >> 14;
        w2t[t] = f2bf(fw2[(l * F_ + k) * F_ + f]);
    }
}

// ---- embedding gather ----
__global__ void k_embed(const float* __restrict__ emb, const int* __restrict__ Z,
                        float* __restrict__ x) {
    int t = blockIdx.x * 256 + threadIdx.x;   // P_*F_ threads
    int p = t >> 7, f = t & 127;
    x[t] = emb[Z[p] * F_ + f];
}

// ---- fp32 GEMM: y[4096,128] = x[4096,128] @ w[128,128] (bias-free) ----
__global__ __launch_bounds__(256) void k_proj(const float* __restrict__ xin,
                                              const float* __restrict__ w,
                                              float* __restrict__ yout) {
    __shared__ float xs[16][128];
    int rb = blockIdx.x * 16;
    int t = threadIdx.x;
#pragma unroll
    for (int i = 0; i < 8; ++i) {
        int idx = i * 256 + t;
        xs[idx >> 7][idx & 127] = xin[rb * 128 + idx];
    }
    __syncthreads();
    int c = t & 127;
    int rg = (t >> 7) * 8;
    float acc[8] = {0, 0, 0, 0, 0, 0, 0, 0};
    for (int k = 0; k < 128; ++k) {
        float wv = w[k * 128 + c];
#pragma unroll
        for (int i = 0; i < 8; ++i) acc[i] += xs[rg + i][k] * wv;
    }
#pragma unroll
    for (int i = 0; i < 8; ++i) yout[(rb + rg + i) * 128 + c] = acc[i];
}

// ---- fused layer kernel (MFMA): 128 edges (2 atoms) per WG, 32 edges per wave ----
// WG = 256 thr = 4 waves. Wave w: atom = blockIdx*2 + (w>>1), edges (w&1)*32..+32
// (two 16-edge tiles, straight-line). Weights read from GLOBAL (cache-hot).
// Per-wave h1 in LDS (GEMM1->GEMM2 same-wave, no barrier). One barrier at the
// final cross-wave atom reduce. R5-proven code style (arrays + full unroll).
__global__ __launch_bounds__(256) void k_layer(
        const float* __restrict__ pos, const int* __restrict__ nbr,
        const float* __restrict__ mask, const float* __restrict__ y,
        const uint16_t* __restrict__ w1t, const float* __restrict__ b1,
        const uint16_t* __restrict__ w2t, const float* __restrict__ b2,
        float* __restrict__ agg)
{
    __shared__ uint16_t h1[4][16 * 128];   // per-wave swizzled H1 tile (4 KiB each)
    __shared__ float wsum[4][128];
    const int wave = threadIdx.x >> 6;
    const int lane = threadIdx.x & 63;
    const int row  = lane & 15;            // A-row lane index (edge within tile)
    const int kg   = lane >> 4;            // k-group
    const int atom = blockIdx.x * 2 + (wave >> 1);
    const int ebase = atom * N_ + (wave & 1) * 32;   // this wave's 32 edges
    const int molbase = atom & ~(A_ - 1);

    const float px = pos[atom * 3 + 0];
    const float py = pos[atom * 3 + 1];
    const float pz = pos[atom * 3 + 2];

    float b1v[8], b2v[8];
#pragma unroll
    for (int nt = 0; nt < 8; ++nt) {
        b1v[nt] = b1[nt * 16 + row];
        b2v[nt] = b2[nt * 16 + row];
    }

    const f32x4 zero = {0.0f, 0.0f, 0.0f, 0.0f};
    uint16_t* hl = h1[wave];
    const float step = 3.8f / 24.0f;
    const float coef = -0.5f / (step * step);

    float pacc[8] = {0.f, 0.f, 0.f, 0.f, 0.f, 0.f, 0.f, 0.f};

#pragma unroll
    for (int mt = 0; mt < 2; ++mt) {
        // --- RBF for this lane's edge (edge = ebase + mt*16 + row; dup across kg) ---
        const int e_mine = ebase + mt * 16 + row;
        const int jrow_mine = molbase + nbr[e_mine];
        const float dx = pos[jrow_mine * 3 + 0] - px;
        const float dy = pos[jrow_mine * 3 + 1] - py;
        const float dz = pos[jrow_mine * 3 + 2] - pz;
        const float r = sqrtf(dx * dx + dy * dy + dz * dz + 1e-9f);
        const float fcr = (r <= CUTOFF_) ? mask[e_mine] : 0.0f;
        bf16x8 a1v;
#pragma unroll
        for (int j = 0; j < 8; ++j) {
            const int k = kg * 8 + j;
            float val = 0.0f;
            if (k < G_) { const float d = r - (OFF0_ + step * (float)k); val = __expf(coef * d * d); }
            a1v[j] = (__bf16)val;
        }

        // GEMM1: [16,32]@[32,128], B from global (cache-hot), ssp -> swizzled h1
#pragma unroll
        for (int nt = 0; nt < 8; ++nt) {
            bf16x8 bfr = *(const bf16x8*)(w1t + (nt * 16 + row) * GP + kg * 8);
            f32x4 acc1 = __builtin_amdgcn_mfma_f32_16x16x32_bf16(a1v, bfr, zero, 0, 0, 0);
            const int col = nt * 16 + row;
#pragma unroll
            for (int j = 0; j < 4; ++j) {
                const int rr = kg * 4 + j;                     // D-row = edge in tile
                const int byt = rr * 256 + ((col * 2) ^ ((rr & 7) << 4));
                *(uint16_t*)((char*)hl + byt) = f2bf(sspf(acc1[j] + b1v[nt]));
            }
        }
        // same-wave LDS write->read; compiler inserts lgkmcnt waits

        // GEMM2: [16,128]@[128,128], K=128 in 4 steps, B from global (cache-hot)
        f32x4 acc2[8];
#pragma unroll
        for (int nt = 0; nt < 8; ++nt) acc2[nt] = zero;
#pragma unroll
        for (int ks = 0; ks < 4; ++ks) {
            const int kbyte = ks * 64 + kg * 16;
            bf16x8 a2 = *(const bf16x8*)((char*)hl + row * 256 + (kbyte ^ ((row & 7) << 4)));
#pragma unroll
            for (int nt = 0; nt < 8; ++nt) {
                bf16x8 bfr = *(const bf16x8*)(w2t + (nt * 16 + row) * F_ + ks * 32 + kg * 8);
                acc2[nt] = __builtin_amdgcn_mfma_f32_16x16x32_bf16(a2, bfr, acc2[nt], 0, 0, 0);
            }
        }

        // fused epilogue: W = (acc2+b2)*fcut, modulate by gathered y, accumulate
        float fc[4]; int jr[4];
#pragma unroll
        for (int j = 0; j < 4; ++j) {
            fc[j] = __shfl(fcr, kg * 4 + j);          // fcut of tile-edge kg*4+j
            jr[j] = __shfl(jrow_mine, kg * 4 + j);    // neighbor row of that edge
        }
#pragma unroll
        for (int nt = 0; nt < 8; ++nt) {
            const int col = nt * 16 + row;
            float s = pacc[nt];
#pragma unroll
            for (int j = 0; j < 4; ++j) {
                const float wv = (acc2[nt][j] + b2v[nt]) * fc[j];
                s += wv * y[(size_t)jr[j] * F_ + col];
            }
            pacc[nt] = s;
        }
    }

    // cross-kg reduce -> per-wave column sums
#pragma unroll
    for (int nt = 0; nt < 8; ++nt) {
        float s = pacc[nt];
        s += __shfl_xor(s, 16);
        s += __shfl_xor(s, 32);
        pacc[nt] = s;
    }
    if (kg == 0) {
#pragma unroll
        for (int nt = 0; nt < 8; ++nt) wsum[wave][nt * 16 + row] = pacc[nt];
    }
    __syncthreads();
    // 2 atoms x 128 cols = 256 threads
    {
        const int a = threadIdx.x >> 7;
        const int c = threadIdx.x & 127;
        agg[(size_t)(blockIdx.x * 2 + a) * F_ + c] = wsum[a * 2][c] + wsum[a * 2 + 1][c];
    }
}

// ---- atom MLP: x += ssp(agg@wa + ba) @ wb + bb ----
__global__ __launch_bounds__(256) void k_out_mlp(
        const float* __restrict__ agg,
        const float* __restrict__ wa, const float* __restrict__ ba,
        const float* __restrict__ wb, const float* __restrict__ bb,
        float* __restrict__ x)
{
    __shared__ float s0[16][128];
    __shared__ float s1[16][128];
    int rb = blockIdx.x * 16;
    int t = threadIdx.x;
#pragma unroll
    for (int i = 0; i < 8; ++i) {
        int idx = i * 256 + t;
        s0[idx >> 7][idx & 127] = agg[rb * 128 + idx];
    }
    __syncthreads();
    int c = t & 127;
    int rg = (t >> 7) * 8;
    float acc[8] = {0, 0, 0, 0, 0, 0, 0, 0};
    for (int k = 0; k < 128; ++k) {
        float wv = wa[k * 128 + c];
#pragma unroll
        for (int i = 0; i < 8; ++i) acc[i] += s0[rg + i][k] * wv;
    }
    float bva = ba[c];
#pragma unroll
    for (int i = 0; i < 8; ++i) s1[rg + i][c] = sspf(acc[i] + bva);
    __syncthreads();
    float acc2[8] = {0, 0, 0, 0, 0, 0, 0, 0};
    for (int k = 0; k < 128; ++k) {
        float wv = wb[k * 128 + c];
#pragma unroll
        for (int i = 0; i < 8; ++i) acc2[i] += s1[rg + i][k] * wv;
    }
    float bvb = bb[c];
#pragma unroll
    for (int i = 0; i < 8; ++i) x[(rb + rg + i) * 128 + c] += acc2[i] + bvb;
}

// ---- final copy fp32 -> fp32 d_out (reference output dtype is float32) ----
__global__ void k_copy_out(const float* __restrict__ x, float* __restrict__ out) {
    int t = blockIdx.x * 256 + threadIdx.x;
    out[t] = x[t];
}

extern "C" void kernel_launch(void* const* d_in, const int* in_sizes, int n_in,
                              void* d_out, int out_size, void* d_ws, size_t ws_size,
                              hipStream_t stream) {
    const float* emb   = (const float*)d_in[0];
    const float* pos   = (const float*)d_in[1];
    const float* fw1   = (const float*)d_in[2];
    const float* fb1   = (const float*)d_in[3];
    const float* fw2   = (const float*)d_in[4];
    const float* fb2   = (const float*)d_in[5];
    const float* in2f  = (const float*)d_in[6];
    const float* f2o_w = (const float*)d_in[7];
    const float* f2o_b = (const float*)d_in[8];
    const float* dns_w = (const float*)d_in[9];
    const float* dns_b = (const float*)d_in[10];
    const int*   Z     = (const int*)d_in[11];
    const int*   nbrs  = (const int*)d_in[12];
    const float* mask  = (const float*)d_in[13];

    char* ws = (char*)d_ws;
    size_t off = 0;
    auto alloc = [&](size_t bytes) {
        char* p = ws + off; off += (bytes + 255) & ~(size_t)255; return p;
    };
    float*    x   = (float*)   alloc((size_t)P_ * F_ * 4);
    float*    y   = (float*)   alloc((size_t)P_ * F_ * 4);
    float*    agg = (float*)   alloc((size_t)P_ * F_ * 4);
    uint16_t* w1t = (uint16_t*)alloc((size_t)L_ * F_ * GP * 2);
    uint16_t* w2t = (uint16_t*)alloc((size_t)L_ * F_ * F_ * 2);
    // total scratch: ~6.4 MB

    k_prepw<<<192, 256, 0, stream>>>(fw1, fw2, w1t, w2t);
    k_embed<<<(P_ * F_) / 256, 256, 0, stream>>>(emb, Z, x);

    for (int l = 0; l < L_; ++l) {
        k_proj<<<P_ / 16, 256, 0, stream>>>(x, in2f + (size_t)l * F_ * F_, y);
        k_layer<<<P_ / 2, 256, 0, stream>>>(pos, nbrs, mask, y,
                                            w1t + (size_t)l * F_ * GP, fb1 + (size_t)l * F_,
                                            w2t + (size_t)l * F_ * F_, fb2 + (size_t)l * F_,
                                            agg);
        k_out_mlp<<<P_ / 16, 256, 0, stream>>>(agg,
                                               f2o_w + (size_t)l * F_ * F_, f2o_b + (size_t)l * F_,
                                               dns_w + (size_t)l * F_ * F_, dns_b + (size_t)l * F_,
                                               x);
    }
    k_copy_out<<<(P_ * F_) / 256, 256, 0, stream>>>(x, (float*)d_out);
}

// Round 10
// 335.124 us; speedup vs baseline: 1.8506x; 1.1668x over previous
//
#include <hip/hip_runtime.h>
#include <stdint.h>

#define B_ 16
#define A_ 256
#define N_ 64
#define F_ 128
#define G_ 25
#define GP 32           // G padded to MFMA K=32
#define L_ 3
#define P_ (B_*A_)      // 4096 atoms
#define CUTOFF_ 5.0f
#define OFF0_ 1.2f

typedef float f32x4 __attribute__((ext_vector_type(4)));
typedef __bf16 bf16x8 __attribute__((ext_vector_type(8)));

__device__ __forceinline__ uint16_t f2bf(float f) {
    union { __bf16 b; uint16_t u; } v; v.b = (__bf16)f;  // RNE hw cvt
    return v.u;
}
// shifted softplus: log(1+e^x) - ln2. Fast 5-op form; inputs here are
// bounded (|x| <~ 10) so no overflow guards needed (exp overflows at 88).
__device__ __forceinline__ float sspf(float x) {
    return fmaf(__log2f(1.0f + __expf(x)), 0.69314718055994531f,
                -0.69314718055994531f);
}

// ---- prep: transpose+pad filter weights to bf16 ----
__global__ void k_prepw(const float* __restrict__ fw1, const float* __restrict__ fw2,
                        uint16_t* __restrict__ w1t, uint16_t* __restrict__ w2t) {
    int t = blockIdx.x * 256 + threadIdx.x;
    if (t < L_ * F_ * GP) {
        int k = t & (GP - 1); int f = (t >> 5) & (F_ - 1); int l = t >> 12;
        float v = (k < G_) ? fw1[(l * G_ + k) * F_ + f] : 0.0f;
        w1t[t] = f2bf(v);
    }
    if (t < L_ * F_ * F_) {
        int k = t & (F_ - 1); int f = (t >> 7) & (F_ - 1); int l = t >> 14;
        w2t[t] = f2bf(fw2[(l * F_ + k) * F_ + f]);
    }
}

// ---- embedding gather ----
__global__ void k_embed(const float* __restrict__ emb, const int* __restrict__ Z,
                        float* __restrict__ x) {
    int t = blockIdx.x * 256 + threadIdx.x;   // P_*F_ threads
    int p = t >> 7, f = t & 127;
    x[t] = emb[Z[p] * F_ + f];
}

// ---- fp32 GEMM: y[4096,128] = x[4096,128] @ w[128,128] (bias-free) ----
__global__ __launch_bounds__(256) void k_proj(const float* __restrict__ xin,
                                              const float* __restrict__ w,
                                              float* __restrict__ yout) {
    __shared__ float xs[16][128];
    int rb = blockIdx.x * 16;
    int t = threadIdx.x;
#pragma unroll
    for (int i = 0; i < 8; ++i) {
        int idx = i * 256 + t;
        xs[idx >> 7][idx & 127] = xin[rb * 128 + idx];
    }
    __syncthreads();
    int c = t & 127;
    int rg = (t >> 7) * 8;
    float acc[8] = {0, 0, 0, 0, 0, 0, 0, 0};
    for (int k = 0; k < 128; ++k) {
        float wv = w[k * 128 + c];
#pragma unroll
        for (int i = 0; i < 8; ++i) acc[i] += xs[rg + i][k] * wv;
    }
#pragma unroll
    for (int i = 0; i < 8; ++i) yout[(rb + rg + i) * 128 + c] = acc[i];
}

// ---- fused layer kernel (MFMA): barrier-free, 1 wave = 1 edge-tile of 16 ----
// WG = 256 thr = 4 INDEPENDENT waves (tile w of atom blockIdx). No barriers:
// per-wave h1 in LDS; cross-tile reduction deferred to k_out_mlp via
// agg4[tile][atom][f] partials. Biases enter through the MFMA C-operand.
__global__ __launch_bounds__(256) void k_layer(
        const float* __restrict__ pos, const int* __restrict__ nbr,
        const float* __restrict__ mask, const float* __restrict__ y,
        const uint16_t* __restrict__ w1t, const float* __restrict__ b1,
        const uint16_t* __restrict__ w2t, const float* __restrict__ b2,
        float* __restrict__ agg4)
{
    __shared__ uint16_t h1[4][16 * 128];   // per-wave swizzled H1 tile (4 KiB each)
    const int wave = threadIdx.x >> 6;
    const int lane = threadIdx.x & 63;
    const int row  = lane & 15;            // A-row / D-col lane index
    const int kg   = lane >> 4;            // k-group
    const int atom = blockIdx.x;           // wave-uniform
    const int molbase = atom & ~(A_ - 1);

    const float px = pos[atom * 3 + 0];    // uniform -> SGPR
    const float py = pos[atom * 3 + 1];
    const float pz = pos[atom * 3 + 2];

    // --- RBF for this lane's edge (edge = wave*16+row; dup across kg) ---
    const int e_mine = atom * N_ + wave * 16 + row;
    const int jrow_mine = molbase + nbr[e_mine];
    const float dx = pos[jrow_mine * 3 + 0] - px;
    const float dy = pos[jrow_mine * 3 + 1] - py;
    const float dz = pos[jrow_mine * 3 + 2] - pz;
    const float r = sqrtf(dx * dx + dy * dy + dz * dz + 1e-9f);
    const float fcr = (r <= CUTOFF_) ? mask[e_mine] : 0.0f;
    const float step = 3.8f / 24.0f;
    const float coef = -0.5f / (step * step);
    bf16x8 a1v;
#pragma unroll
    for (int j = 0; j < 8; ++j) {
        const int k = kg * 8 + j;
        float val = 0.0f;
        if (k < G_) { const float d = r - (OFF0_ + step * (float)k); val = __expf(coef * d * d); }
        a1v[j] = (__bf16)val;
    }

    uint16_t* hl = h1[wave];

    // GEMM1: [16,32]@[32,128], bias in C, ssp -> XOR-swizzled per-wave h1
#pragma unroll
    for (int nt = 0; nt < 8; ++nt) {
        const float b1v = b1[nt * 16 + row];
        const f32x4 c1 = {b1v, b1v, b1v, b1v};
        bf16x8 bfr = *(const bf16x8*)(w1t + (nt * 16 + row) * GP + kg * 8);
        f32x4 acc1 = __builtin_amdgcn_mfma_f32_16x16x32_bf16(a1v, bfr, c1, 0, 0, 0);
        const int col = nt * 16 + row;
#pragma unroll
        for (int j = 0; j < 4; ++j) {
            const int rr = kg * 4 + j;                     // D-row = edge in tile
            const int byt = rr * 256 + ((col * 2) ^ ((rr & 7) << 4));
            *(uint16_t*)((char*)hl + byt) = f2bf(sspf(acc1[j]));
        }
    }
    // same-wave LDS write->read; compiler inserts lgkmcnt waits (no barrier)

    // GEMM2: [16,128]@[128,128], K=128 in 4 steps, bias in C
    f32x4 acc2[8];
#pragma unroll
    for (int nt = 0; nt < 8; ++nt) {
        const float b2v = b2[nt * 16 + row];
        acc2[nt] = (f32x4){b2v, b2v, b2v, b2v};
    }
#pragma unroll
    for (int ks = 0; ks < 4; ++ks) {
        const int kbyte = ks * 64 + kg * 16;
        bf16x8 a2 = *(const bf16x8*)((char*)hl + row * 256 + (kbyte ^ ((row & 7) << 4)));
#pragma unroll
        for (int nt = 0; nt < 8; ++nt) {
            bf16x8 bfr = *(const bf16x8*)(w2t + (nt * 16 + row) * F_ + ks * 32 + kg * 8);
            acc2[nt] = __builtin_amdgcn_mfma_f32_16x16x32_bf16(a2, bfr, acc2[nt], 0, 0, 0);
        }
    }

    // fused epilogue: W = acc2*fcut, modulate by gathered y, accumulate
    float fc[4]; int jr[4];
#pragma unroll
    for (int j = 0; j < 4; ++j) {
        fc[j] = __shfl(fcr, kg * 4 + j);          // fcut of tile-edge kg*4+j
        jr[j] = __shfl(jrow_mine, kg * 4 + j);    // neighbor row of that edge
    }
    float pacc[8];
#pragma unroll
    for (int nt = 0; nt < 8; ++nt) {
        const int col = nt * 16 + row;
        float s = 0.0f;
#pragma unroll
        for (int j = 0; j < 4; ++j) {
            s += (acc2[nt][j] * fc[j]) * y[jr[j] * F_ + col];
        }
        // cross-kg reduce
        s += __shfl_xor(s, 16);
        s += __shfl_xor(s, 32);
        pacc[nt] = s;
    }
    if (kg == 0) {
#pragma unroll
        for (int nt = 0; nt < 8; ++nt)
            agg4[((size_t)wave * P_ + atom) * F_ + nt * 16 + row] = pacc[nt];
    }
}

// ---- atom MLP: x += ssp(sum4(agg4)@wa + ba) @ wb + bb ----
__global__ __launch_bounds__(256) void k_out_mlp(
        const float* __restrict__ agg4,
        const float* __restrict__ wa, const float* __restrict__ ba,
        const float* __restrict__ wb, const float* __restrict__ bb,
        float* __restrict__ x)
{
    __shared__ float s0[16][128];
    __shared__ float s1[16][128];
    int rb = blockIdx.x * 16;
    int t = threadIdx.x;
#pragma unroll
    for (int i = 0; i < 8; ++i) {
        int idx = i * 256 + t;
        size_t base = (size_t)rb * 128 + idx;
        s0[idx >> 7][idx & 127] = agg4[base] + agg4[(size_t)P_ * F_ + base] +
                                  agg4[2 * (size_t)P_ * F_ + base] +
                                  agg4[3 * (size_t)P_ * F_ + base];
    }
    __syncthreads();
    int c = t & 127;
    int rg = (t >> 7) * 8;
    float acc[8] = {0, 0, 0, 0, 0, 0, 0, 0};
    for (int k = 0; k < 128; ++k) {
        float wv = wa[k * 128 + c];
#pragma unroll
        for (int i = 0; i < 8; ++i) acc[i] += s0[rg + i][k] * wv;
    }
    float bva = ba[c];
#pragma unroll
    for (int i = 0; i < 8; ++i) s1[rg + i][c] = sspf(acc[i] + bva);
    __syncthreads();
    float acc2[8] = {0, 0, 0, 0, 0, 0, 0, 0};
    for (int k = 0; k < 128; ++k) {
        float wv = wb[k * 128 + c];
#pragma unroll
        for (int i = 0; i < 8; ++i) acc2[i] += s1[rg + i][k] * wv;
    }
    float bvb = bb[c];
#pragma unroll
    for (int i = 0; i < 8; ++i) x[(rb + rg + i) * 128 + c] += acc2[i] + bvb;
}

// ---- final copy fp32 -> fp32 d_out (reference output dtype is float32) ----
__global__ void k_copy_out(const float* __restrict__ x, float* __restrict__ out) {
    int t = blockIdx.x * 256 + threadIdx.x;
    out[t] = x[t];
}

extern "C" void kernel_launch(void* const* d_in, const int* in_sizes, int n_in,
                              void* d_out, int out_size, void* d_ws, size_t ws_size,
                              hipStream_t stream) {
    const float* emb   = (const float*)d_in[0];
    const float* pos   = (const float*)d_in[1];
    const float* fw1   = (const float*)d_in[2];
    const float* fb1   = (const float*)d_in[3];
    const float* fw2   = (const float*)d_in[4];
    const float* fb2   = (const float*)d_in[5];
    const float* in2f  = (const float*)d_in[6];
    const float* f2o_w = (const float*)d_in[7];
    const float* f2o_b = (const float*)d_in[8];
    const float* dns_w = (const float*)d_in[9];
    const float* dns_b = (const float*)d_in[10];
    const int*   Z     = (const int*)d_in[11];
    const int*   nbrs  = (const int*)d_in[12];
    const float* mask  = (const float*)d_in[13];

    char* ws = (char*)d_ws;
    size_t off = 0;
    auto alloc = [&](size_t bytes) {
        char* p = ws + off; off += (bytes + 255) & ~(size_t)255; return p;
    };
    float*    x    = (float*)   alloc((size_t)P_ * F_ * 4);
    float*    y    = (float*)   alloc((size_t)P_ * F_ * 4);
    float*    agg4 = (float*)   alloc((size_t)4 * P_ * F_ * 4);   // 8 MB partials
    uint16_t* w1t  = (uint16_t*)alloc((size_t)L_ * F_ * GP * 2);
    uint16_t* w2t  = (uint16_t*)alloc((size_t)L_ * F_ * F_ * 2);
    // total scratch: ~12.3 MB

    k_prepw<<<192, 256, 0, stream>>>(fw1, fw2, w1t, w2t);
    k_embed<<<(P_ * F_) / 256, 256, 0, stream>>>(emb, Z, x);

    for (int l = 0; l < L_; ++l) {
        k_proj<<<P_ / 16, 256, 0, stream>>>(x, in2f + (size_t)l * F_ * F_, y);
        k_layer<<<P_, 256, 0, stream>>>(pos, nbrs, mask, y,
                                        w1t + (size_t)l * F_ * GP, fb1 + (size_t)l * F_,
                                        w2t + (size_t)l * F_ * F_, fb2 + (size_t)l * F_,
                                        agg4);
        k_out_mlp<<<P_ / 16, 256, 0, stream>>>(agg4,
                                               f2o_w + (size_t)l * F_ * F_, f2o_b + (size_t)l * F_,
                                               dns_w + (size_t)l * F_ * F_, dns_b + (size_t)l * F_,
                                               x);
    }
    k_copy_out<<<(P_ * F_) / 256, 256, 0, stream>>>(x, (float*)d_out);
}

// Round 11
// 213.511 us; speedup vs baseline: 2.9047x; 1.5696x over previous
//
#include <hip/hip_runtime.h>
#include <stdint.h>

#define B_ 16
#define A_ 256
#define N_ 64
#define F_ 128
#define G_ 25
#define GP 32           // G padded to MFMA K=32
#define L_ 3
#define P_ (B_*A_)      // 4096 atoms
#define CUTOFF_ 5.0f
#define OFF0_ 1.2f

typedef float f32x4 __attribute__((ext_vector_type(4)));
typedef __bf16 bf16x8 __attribute__((ext_vector_type(8)));

__device__ __forceinline__ uint16_t f2bf(float f) {
    union { __bf16 b; uint16_t u; } v; v.b = (__bf16)f;  // RNE hw cvt
    return v.u;
}
// shifted softplus: log(1+e^x) - ln2. Fast form; inputs bounded (|x|<~20).
__device__ __forceinline__ float sspf(float x) {
    return fmaf(__log2f(1.0f + __expf(x)), 0.69314718055994531f,
                -0.69314718055994531f);
}

// ---- prep: transpose+pad filter weights to bf16 ----
__global__ void k_prepw(const float* __restrict__ fw1, const float* __restrict__ fw2,
                        uint16_t* __restrict__ w1t, uint16_t* __restrict__ w2t) {
    int t = blockIdx.x * 256 + threadIdx.x;
    if (t < L_ * F_ * GP) {
        int k = t & (GP - 1); int f = (t >> 5) & (F_ - 1); int l = t >> 12;
        float v = (k < G_) ? fw1[(l * G_ + k) * F_ + f] : 0.0f;
        w1t[t] = f2bf(v);
    }
    if (t < L_ * F_ * F_) {
        int k = t & (F_ - 1); int f = (t >> 7) & (F_ - 1); int l = t >> 14;
        w2t[t] = f2bf(fw2[(l * F_ + k) * F_ + f]);
    }
}

// ---- embedding gather ----
__global__ void k_embed(const float* __restrict__ emb, const int* __restrict__ Z,
                        float* __restrict__ x) {
    int t = blockIdx.x * 256 + threadIdx.x;   // P_*F_ threads
    int p = t >> 7, f = t & 127;
    x[t] = emb[Z[p] * F_ + f];
}

// ---- fp32 GEMM: y[4096,128] = x[4096,128] @ w[128,128] (bias-free) ----
__global__ __launch_bounds__(256) void k_proj(const float* __restrict__ xin,
                                              const float* __restrict__ w,
                                              float* __restrict__ yout) {
    __shared__ float xs[16][128];
    int rb = blockIdx.x * 16;
    int t = threadIdx.x;
#pragma unroll
    for (int i = 0; i < 8; ++i) {
        int idx = i * 256 + t;
        xs[idx >> 7][idx & 127] = xin[rb * 128 + idx];
    }
    __syncthreads();
    int c = t & 127;
    int rg = (t >> 7) * 8;
    float acc[8] = {0, 0, 0, 0, 0, 0, 0, 0};
    for (int k = 0; k < 128; ++k) {
        float wv = w[k * 128 + c];
#pragma unroll
        for (int i = 0; i < 8; ++i) acc[i] += xs[rg + i][k] * wv;
    }
#pragma unroll
    for (int i = 0; i < 8; ++i) yout[(rb + rg + i) * 128 + c] = acc[i];
}

// ---- fused layer kernel (MFMA): 1 wave = 1 edge-tile of 16, w2 LDS-staged ----
// WG = 256 thr = 4 waves (tile w of atom blockIdx). One barrier after w2
// staging, then waves drift. Per-wave h1; cross-tile reduction deferred to
// k_out_mlp via agg4[tile][atom][f]. Biases via MFMA C-operand.
__global__ __launch_bounds__(256) void k_layer(
        const float* __restrict__ pos, const int* __restrict__ nbr,
        const float* __restrict__ mask, const float* __restrict__ y,
        const uint16_t* __restrict__ w1t, const float* __restrict__ b1,
        const uint16_t* __restrict__ w2t, const float* __restrict__ b2,
        float* __restrict__ agg4)
{
    __shared__ uint16_t w2s[F_ * F_];      // 32 KB, swizzled: f*256B + (k2 ^ ((f&7)<<4))
    __shared__ uint16_t h1[4][16 * 128];   // per-wave swizzled H1 tile (4 KiB each)

    // ---- cooperative w2 staging: 2048 16B-vectors, coalesced ----
    {
        const int t = threadIdx.x;
#pragma unroll
        for (int i = 0; i < 8; ++i) {
            const int idx = i * 256 + t;
            const int f2 = idx >> 4, kc2 = (idx & 15) * 8;
            uint4 v2 = *(const uint4*)(w2t + f2 * F_ + kc2);
            *(uint4*)((char*)w2s + f2 * 256 + ((kc2 * 2) ^ ((f2 & 7) << 4))) = v2;
        }
    }
    __syncthreads();

    const int wave = threadIdx.x >> 6;
    const int lane = threadIdx.x & 63;
    const int row  = lane & 15;            // A-row / D-col lane index
    const int kg   = lane >> 4;            // k-group
    const int atom = blockIdx.x;           // wave-uniform
    const int molbase = atom & ~(A_ - 1);

    const float px = pos[atom * 3 + 0];    // uniform -> SGPR
    const float py = pos[atom * 3 + 1];
    const float pz = pos[atom * 3 + 2];

    // --- RBF for this lane's edge (edge = wave*16+row; dup across kg) ---
    const int e_mine = atom * N_ + wave * 16 + row;
    const int jrow_mine = molbase + nbr[e_mine];
    const float dx = pos[jrow_mine * 3 + 0] - px;
    const float dy = pos[jrow_mine * 3 + 1] - py;
    const float dz = pos[jrow_mine * 3 + 2] - pz;
    const float r = sqrtf(dx * dx + dy * dy + dz * dz + 1e-9f);
    const float fcr = (r <= CUTOFF_) ? mask[e_mine] : 0.0f;
    const float step = 3.8f / 24.0f;
    const float coef = -0.5f / (step * step);
    bf16x8 a1v;
#pragma unroll
    for (int j = 0; j < 8; ++j) {
        const int k = kg * 8 + j;
        float val = 0.0f;
        if (k < G_) { const float d = r - (OFF0_ + step * (float)k); val = __expf(coef * d * d); }
        a1v[j] = (__bf16)val;
    }

    uint16_t* hl = h1[wave];

    // GEMM1: [16,32]@[32,128], B from global (8 loads, cache-hot), bias in C,
    // ssp -> XOR-swizzled per-wave h1
#pragma unroll
    for (int nt = 0; nt < 8; ++nt) {
        const float b1v = b1[nt * 16 + row];
        const f32x4 c1 = {b1v, b1v, b1v, b1v};
        bf16x8 bfr = *(const bf16x8*)(w1t + (nt * 16 + row) * GP + kg * 8);
        f32x4 acc1 = __builtin_amdgcn_mfma_f32_16x16x32_bf16(a1v, bfr, c1, 0, 0, 0);
        const int col = nt * 16 + row;
#pragma unroll
        for (int j = 0; j < 4; ++j) {
            const int rr = kg * 4 + j;                     // D-row = edge in tile
            const int byt = rr * 256 + ((col * 2) ^ ((rr & 7) << 4));
            *(uint16_t*)((char*)hl + byt) = f2bf(sspf(acc1[j]));
        }
    }
    // same-wave LDS write->read; compiler inserts lgkmcnt waits (no barrier)

    // GEMM2: [16,128]@[128,128], K=128 in 4 steps, B from LDS, bias in C
    f32x4 acc2[8];
#pragma unroll
    for (int nt = 0; nt < 8; ++nt) {
        const float b2v = b2[nt * 16 + row];
        acc2[nt] = (f32x4){b2v, b2v, b2v, b2v};
    }
#pragma unroll
    for (int ks = 0; ks < 4; ++ks) {
        const int kbyte = ks * 64 + kg * 16;
        bf16x8 a2 = *(const bf16x8*)((char*)hl + row * 256 + (kbyte ^ ((row & 7) << 4)));
#pragma unroll
        for (int nt = 0; nt < 8; ++nt) {
            bf16x8 bfr = *(const bf16x8*)((char*)w2s + (nt * 16 + row) * 256 +
                                          (kbyte ^ ((row & 7) << 4)));
            acc2[nt] = __builtin_amdgcn_mfma_f32_16x16x32_bf16(a2, bfr, acc2[nt], 0, 0, 0);
        }
    }

    // fused epilogue: W = acc2*fcut, modulate by gathered y, accumulate
    float fc[4]; int jr[4];
#pragma unroll
    for (int j = 0; j < 4; ++j) {
        fc[j] = __shfl(fcr, kg * 4 + j);          // fcut of tile-edge kg*4+j
        jr[j] = __shfl(jrow_mine, kg * 4 + j);    // neighbor row of that edge
    }
    float pacc[8];
#pragma unroll
    for (int nt = 0; nt < 8; ++nt) {
        const int col = nt * 16 + row;
        float s = 0.0f;
#pragma unroll
        for (int j = 0; j < 4; ++j) {
            s += (acc2[nt][j] * fc[j]) * y[jr[j] * F_ + col];
        }
        // cross-kg reduce
        s += __shfl_xor(s, 16);
        s += __shfl_xor(s, 32);
        pacc[nt] = s;
    }
    if (kg == 0) {
#pragma unroll
        for (int nt = 0; nt < 8; ++nt)
            agg4[((size_t)wave * P_ + atom) * F_ + nt * 16 + row] = pacc[nt];
    }
}

// ---- atom MLP: x += ssp(sum4(agg4)@wa + ba) @ wb + bb ----
__global__ __launch_bounds__(256) void k_out_mlp(
        const float* __restrict__ agg4,
        const float* __restrict__ wa, const float* __restrict__ ba,
        const float* __restrict__ wb, const float* __restrict__ bb,
        float* __restrict__ x)
{
    __shared__ float s0[16][128];
    __shared__ float s1[16][128];
    int rb = blockIdx.x * 16;
    int t = threadIdx.x;
#pragma unroll
    for (int i = 0; i < 8; ++i) {
        int idx = i * 256 + t;
        size_t base = (size_t)rb * 128 + idx;
        s0[idx >> 7][idx & 127] = agg4[base] + agg4[(size_t)P_ * F_ + base] +
                                  agg4[2 * (size_t)P_ * F_ + base] +
                                  agg4[3 * (size_t)P_ * F_ + base];
    }
    __syncthreads();
    int c = t & 127;
    int rg = (t >> 7) * 8;
    float acc[8] = {0, 0, 0, 0, 0, 0, 0, 0};
    for (int k = 0; k < 128; ++k) {
        float wv = wa[k * 128 + c];
#pragma unroll
        for (int i = 0; i < 8; ++i) acc[i] += s0[rg + i][k] * wv;
    }
    float bva = ba[c];
#pragma unroll
    for (int i = 0; i < 8; ++i) s1[rg + i][c] = sspf(acc[i] + bva);
    __syncthreads();
    float acc2[8] = {0, 0, 0, 0, 0, 0, 0, 0};
    for (int k = 0; k < 128; ++k) {
        float wv = wb[k * 128 + c];
#pragma unroll
        for (int i = 0; i < 8; ++i) acc2[i] += s1[rg + i][k] * wv;
    }
    float bvb = bb[c];
#pragma unroll
    for (int i = 0; i < 8; ++i) x[(rb + rg + i) * 128 + c] += acc2[i] + bvb;
}

// ---- final copy fp32 -> fp32 d_out (reference output dtype is float32) ----
__global__ void k_copy_out(const float* __restrict__ x, float* __restrict__ out) {
    int t = blockIdx.x * 256 + threadIdx.x;
    out[t] = x[t];
}

extern "C" void kernel_launch(void* const* d_in, const int* in_sizes, int n_in,
                              void* d_out, int out_size, void* d_ws, size_t ws_size,
                              hipStream_t stream) {
    const float* emb   = (const float*)d_in[0];
    const float* pos   = (const float*)d_in[1];
    const float* fw1   = (const float*)d_in[2];
    const float* fb1   = (const float*)d_in[3];
    const float* fw2   = (const float*)d_in[4];
    const float* fb2   = (const float*)d_in[5];
    const float* in2f  = (const float*)d_in[6];
    const float* f2o_w = (const float*)d_in[7];
    const float* f2o_b = (const float*)d_in[8];
    const float* dns_w = (const float*)d_in[9];
    const float* dns_b = (const float*)d_in[10];
    const int*   Z     = (const int*)d_in[11];
    const int*   nbrs  = (const int*)d_in[12];
    const float* mask  = (const float*)d_in[13];

    char* ws = (char*)d_ws;
    size_t off = 0;
    auto alloc = [&](size_t bytes) {
        char* p = ws + off; off += (bytes + 255) & ~(size_t)255; return p;
    };
    float*    x    = (float*)   alloc((size_t)P_ * F_ * 4);
    float*    y    = (float*)   alloc((size_t)P_ * F_ * 4);
    float*    agg4 = (float*)   alloc((size_t)4 * P_ * F_ * 4);   // 8 MB partials
    uint16_t* w1t  = (uint16_t*)alloc((size_t)L_ * F_ * GP * 2);
    uint16_t* w2t  = (uint16_t*)alloc((size_t)L_ * F_ * F_ * 2);
    // total scratch: ~12.3 MB

    k_prepw<<<192, 256, 0, stream>>>(fw1, fw2, w1t, w2t);
    k_embed<<<(P_ * F_) / 256, 256, 0, stream>>>(emb, Z, x);

    for (int l = 0; l < L_; ++l) {
        k_proj<<<P_ / 16, 256, 0, stream>>>(x, in2f + (size_t)l * F_ * F_, y);
        k_layer<<<P_, 256, 0, stream>>>(pos, nbrs, mask, y,
                                        w1t + (size_t)l * F_ * GP, fb1 + (size_t)l * F_,
                                        w2t + (size_t)l * F_ * F_, fb2 + (size_t)l * F_,
                                        agg4);
        k_out_mlp<<<P_ / 16, 256, 0, stream>>>(agg4,
                                               f2o_w + (size_t)l * F_ * F_, f2o_b + (size_t)l * F_,
                                               dns_w + (size_t)l * F_ * F_, dns_b + (size_t)l * F_,
                                               x);
    }
    k_copy_out<<<(P_ * F_) / 256, 256, 0, stream>>>(x, (float*)d_out);
}

// Round 12
// 195.236 us; speedup vs baseline: 3.1765x; 1.0936x over previous
//
#include <hip/hip_runtime.h>
#include <stdint.h>

#define B_ 16
#define A_ 256
#define N_ 64
#define F_ 128
#define G_ 25
#define GP 32           // G padded to MFMA K=32
#define L_ 3
#define P_ (B_*A_)      // 4096 atoms
#define CUTOFF_ 5.0f
#define OFF0_ 1.2f

typedef float f32x4 __attribute__((ext_vector_type(4)));
typedef __bf16 bf16x8 __attribute__((ext_vector_type(8)));

__device__ __forceinline__ uint16_t f2bf(float f) {
    union { __bf16 b; uint16_t u; } v; v.b = (__bf16)f;  // RNE hw cvt
    return v.u;
}
// shifted softplus: log(1+e^x) - ln2. Fast form; inputs bounded (|x|<~20).
__device__ __forceinline__ float sspf(float x) {
    return fmaf(__log2f(1.0f + __expf(x)), 0.69314718055994531f,
                -0.69314718055994531f);
}

// ---- prep: transpose+pad all GEMM weights to bf16 [f][k] ----
__global__ void k_prepw(const float* __restrict__ fw1, const float* __restrict__ fw2,
                        const float* __restrict__ in2f, const float* __restrict__ f2ow,
                        const float* __restrict__ dnsw,
                        uint16_t* __restrict__ w1t, uint16_t* __restrict__ w2t,
                        uint16_t* __restrict__ in2ft, uint16_t* __restrict__ f2ot,
                        uint16_t* __restrict__ dnst) {
    int t = blockIdx.x * 256 + threadIdx.x;
    if (t < L_ * F_ * GP) {
        int k = t & (GP - 1); int f = (t >> 5) & (F_ - 1); int l = t >> 12;
        float v = (k < G_) ? fw1[(l * G_ + k) * F_ + f] : 0.0f;
        w1t[t] = f2bf(v);
    }
    if (t < L_ * F_ * F_) {
        int k = t & (F_ - 1); int f = (t >> 7) & (F_ - 1); int l = t >> 14;
        const size_t src = (size_t)(l * F_ + k) * F_ + f;
        w2t[t]   = f2bf(fw2[src]);
        in2ft[t] = f2bf(in2f[src]);
        f2ot[t]  = f2bf(f2ow[src]);
        dnst[t]  = f2bf(dnsw[src]);
    }
}

// ---- embedding gather: fp32 x + bf16 shadow ----
__global__ void k_embed(const float* __restrict__ emb, const int* __restrict__ Z,
                        float* __restrict__ x, uint16_t* __restrict__ xbf) {
    int t = blockIdx.x * 256 + threadIdx.x;   // P_*F_ threads
    int p = t >> 7, f = t & 127;
    float v = emb[Z[p] * F_ + f];
    x[t] = v;
    xbf[t] = f2bf(v);
}

// ---- MFMA GEMM: y[4096,128] = xbf @ in2ft^T (bias-free), fp32 out ----
// WG = 4 waves; wave handles 16 rows x 128 cols, K=128.
__global__ __launch_bounds__(256) void k_proj(const uint16_t* __restrict__ xbf,
                                              const uint16_t* __restrict__ wt,
                                              float* __restrict__ y) {
    const int wave = threadIdx.x >> 6;
    const int lane = threadIdx.x & 63;
    const int row  = lane & 15;
    const int kg   = lane >> 4;
    const int rb   = blockIdx.x * 64 + wave * 16;

    f32x4 acc[8];
#pragma unroll
    for (int nt = 0; nt < 8; ++nt) acc[nt] = (f32x4){0.f, 0.f, 0.f, 0.f};
#pragma unroll
    for (int ks = 0; ks < 4; ++ks) {
        bf16x8 a = *(const bf16x8*)(xbf + (size_t)(rb + row) * F_ + ks * 32 + kg * 8);
#pragma unroll
        for (int nt = 0; nt < 8; ++nt) {
            bf16x8 bfr = *(const bf16x8*)(wt + (nt * 16 + row) * F_ + ks * 32 + kg * 8);
            acc[nt] = __builtin_amdgcn_mfma_f32_16x16x32_bf16(a, bfr, acc[nt], 0, 0, 0);
        }
    }
#pragma unroll
    for (int nt = 0; nt < 8; ++nt)
#pragma unroll
        for (int j = 0; j < 4; ++j)
            y[(size_t)(rb + kg * 4 + j) * F_ + nt * 16 + row] = acc[nt][j];
}

// ---- fused layer kernel (MFMA): 1 wave = 1 edge-tile of 16, w2 LDS-staged ----
// (unchanged from round 11)
__global__ __launch_bounds__(256) void k_layer(
        const float* __restrict__ pos, const int* __restrict__ nbr,
        const float* __restrict__ mask, const float* __restrict__ y,
        const uint16_t* __restrict__ w1t, const float* __restrict__ b1,
        const uint16_t* __restrict__ w2t, const float* __restrict__ b2,
        float* __restrict__ agg4)
{
    __shared__ uint16_t w2s[F_ * F_];      // 32 KB, swizzled: f*256B + (k2 ^ ((f&7)<<4))
    __shared__ uint16_t h1[4][16 * 128];   // per-wave swizzled H1 tile (4 KiB each)

    {
        const int t = threadIdx.x;
#pragma unroll
        for (int i = 0; i < 8; ++i) {
            const int idx = i * 256 + t;
            const int f2 = idx >> 4, kc2 = (idx & 15) * 8;
            uint4 v2 = *(const uint4*)(w2t + f2 * F_ + kc2);
            *(uint4*)((char*)w2s + f2 * 256 + ((kc2 * 2) ^ ((f2 & 7) << 4))) = v2;
        }
    }
    __syncthreads();

    const int wave = threadIdx.x >> 6;
    const int lane = threadIdx.x & 63;
    const int row  = lane & 15;
    const int kg   = lane >> 4;
    const int atom = blockIdx.x;
    const int molbase = atom & ~(A_ - 1);

    const float px = pos[atom * 3 + 0];
    const float py = pos[atom * 3 + 1];
    const float pz = pos[atom * 3 + 2];

    const int e_mine = atom * N_ + wave * 16 + row;
    const int jrow_mine = molbase + nbr[e_mine];
    const float dx = pos[jrow_mine * 3 + 0] - px;
    const float dy = pos[jrow_mine * 3 + 1] - py;
    const float dz = pos[jrow_mine * 3 + 2] - pz;
    const float r = sqrtf(dx * dx + dy * dy + dz * dz + 1e-9f);
    const float fcr = (r <= CUTOFF_) ? mask[e_mine] : 0.0f;
    const float step = 3.8f / 24.0f;
    const float coef = -0.5f / (step * step);
    bf16x8 a1v;
#pragma unroll
    for (int j = 0; j < 8; ++j) {
        const int k = kg * 8 + j;
        float val = 0.0f;
        if (k < G_) { const float d = r - (OFF0_ + step * (float)k); val = __expf(coef * d * d); }
        a1v[j] = (__bf16)val;
    }

    uint16_t* hl = h1[wave];

#pragma unroll
    for (int nt = 0; nt < 8; ++nt) {
        const float b1v = b1[nt * 16 + row];
        const f32x4 c1 = {b1v, b1v, b1v, b1v};
        bf16x8 bfr = *(const bf16x8*)(w1t + (nt * 16 + row) * GP + kg * 8);
        f32x4 acc1 = __builtin_amdgcn_mfma_f32_16x16x32_bf16(a1v, bfr, c1, 0, 0, 0);
        const int col = nt * 16 + row;
#pragma unroll
        for (int j = 0; j < 4; ++j) {
            const int rr = kg * 4 + j;
            const int byt = rr * 256 + ((col * 2) ^ ((rr & 7) << 4));
            *(uint16_t*)((char*)hl + byt) = f2bf(sspf(acc1[j]));
        }
    }

    f32x4 acc2[8];
#pragma unroll
    for (int nt = 0; nt < 8; ++nt) {
        const float b2v = b2[nt * 16 + row];
        acc2[nt] = (f32x4){b2v, b2v, b2v, b2v};
    }
#pragma unroll
    for (int ks = 0; ks < 4; ++ks) {
        const int kbyte = ks * 64 + kg * 16;
        bf16x8 a2 = *(const bf16x8*)((char*)hl + row * 256 + (kbyte ^ ((row & 7) << 4)));
#pragma unroll
        for (int nt = 0; nt < 8; ++nt) {
            bf16x8 bfr = *(const bf16x8*)((char*)w2s + (nt * 16 + row) * 256 +
                                          (kbyte ^ ((row & 7) << 4)));
            acc2[nt] = __builtin_amdgcn_mfma_f32_16x16x32_bf16(a2, bfr, acc2[nt], 0, 0, 0);
        }
    }

    float fc[4]; int jr[4];
#pragma unroll
    for (int j = 0; j < 4; ++j) {
        fc[j] = __shfl(fcr, kg * 4 + j);
        jr[j] = __shfl(jrow_mine, kg * 4 + j);
    }
    float pacc[8];
#pragma unroll
    for (int nt = 0; nt < 8; ++nt) {
        const int col = nt * 16 + row;
        float s = 0.0f;
#pragma unroll
        for (int j = 0; j < 4; ++j) {
            s += (acc2[nt][j] * fc[j]) * y[jr[j] * F_ + col];
        }
        s += __shfl_xor(s, 16);
        s += __shfl_xor(s, 32);
        pacc[nt] = s;
    }
    if (kg == 0) {
#pragma unroll
        for (int nt = 0; nt < 8; ++nt)
            agg4[((size_t)wave * P_ + atom) * F_ + nt * 16 + row] = pacc[nt];
    }
}

// ---- atom MLP (MFMA): x += ssp(sum4(agg4)@f2o + ba) @ dns + bb ----
// WG = 4 waves; wave = 16 rows. Two chained GEMMs via per-wave swizzled LDS.
// Writes fp32 x, bf16 xbf, and (optionally) final output.
__global__ __launch_bounds__(256) void k_out_mlp(
        const float* __restrict__ agg4,
        const uint16_t* __restrict__ f2ot, const float* __restrict__ ba,
        const uint16_t* __restrict__ dnst, const float* __restrict__ bb,
        float* __restrict__ x, uint16_t* __restrict__ xbf,
        float* __restrict__ out)
{
    __shared__ uint16_t hs[4][16 * 128];
    const int wave = threadIdx.x >> 6;
    const int lane = threadIdx.x & 63;
    const int row  = lane & 15;
    const int kg   = lane >> 4;
    const int rb   = blockIdx.x * 64 + wave * 16;
    uint16_t* hl = hs[wave];

    // GEMM_a: A = bf16(sum of 4 agg4 partials), B = f2ot, C = bias
    f32x4 acc[8];
#pragma unroll
    for (int nt = 0; nt < 8; ++nt) {
        const float bav = ba[nt * 16 + row];
        acc[nt] = (f32x4){bav, bav, bav, bav};
    }
#pragma unroll
    for (int ks = 0; ks < 4; ++ks) {
        const size_t base = (size_t)(rb + row) * F_ + ks * 32 + kg * 8;
        float4 u0 = *(const float4*)(agg4 + base);
        float4 u1 = *(const float4*)(agg4 + base + 4);
#pragma unroll
        for (int p = 1; p < 4; ++p) {
            const size_t pb = (size_t)p * P_ * F_ + base;
            float4 v0 = *(const float4*)(agg4 + pb);
            float4 v1 = *(const float4*)(agg4 + pb + 4);
            u0.x += v0.x; u0.y += v0.y; u0.z += v0.z; u0.w += v0.w;
            u1.x += v1.x; u1.y += v1.y; u1.z += v1.z; u1.w += v1.w;
        }
        bf16x8 a;
        a[0] = (__bf16)u0.x; a[1] = (__bf16)u0.y; a[2] = (__bf16)u0.z; a[3] = (__bf16)u0.w;
        a[4] = (__bf16)u1.x; a[5] = (__bf16)u1.y; a[6] = (__bf16)u1.z; a[7] = (__bf16)u1.w;
#pragma unroll
        for (int nt = 0; nt < 8; ++nt) {
            bf16x8 bfr = *(const bf16x8*)(f2ot + (nt * 16 + row) * F_ + ks * 32 + kg * 8);
            acc[nt] = __builtin_amdgcn_mfma_f32_16x16x32_bf16(a, bfr, acc[nt], 0, 0, 0);
        }
    }
    // ssp -> swizzled LDS (D row rr = m, col = n)
#pragma unroll
    for (int nt = 0; nt < 8; ++nt) {
        const int col = nt * 16 + row;
#pragma unroll
        for (int j = 0; j < 4; ++j) {
            const int rr = kg * 4 + j;
            const int byt = rr * 256 + ((col * 2) ^ ((rr & 7) << 4));
            *(uint16_t*)((char*)hl + byt) = f2bf(sspf(acc[nt][j]));
        }
    }
    // same-wave LDS write->read (no barrier)

    // GEMM_b: A = hl, B = dnst, C = bias bb
    f32x4 acc2[8];
#pragma unroll
    for (int nt = 0; nt < 8; ++nt) {
        const float bbv = bb[nt * 16 + row];
        acc2[nt] = (f32x4){bbv, bbv, bbv, bbv};
    }
#pragma unroll
    for (int ks = 0; ks < 4; ++ks) {
        const int kbyte = ks * 64 + kg * 16;
        bf16x8 a2 = *(const bf16x8*)((char*)hl + row * 256 + (kbyte ^ ((row & 7) << 4)));
#pragma unroll
        for (int nt = 0; nt < 8; ++nt) {
            bf16x8 bfr = *(const bf16x8*)(dnst + (nt * 16 + row) * F_ + ks * 32 + kg * 8);
            acc2[nt] = __builtin_amdgcn_mfma_f32_16x16x32_bf16(a2, bfr, acc2[nt], 0, 0, 0);
        }
    }
    // epilogue: residual add, write x / xbf / (final) out
#pragma unroll
    for (int nt = 0; nt < 8; ++nt) {
#pragma unroll
        for (int j = 0; j < 4; ++j) {
            const size_t idx = (size_t)(rb + kg * 4 + j) * F_ + nt * 16 + row;
            const float val = acc2[nt][j] + x[idx];
            x[idx] = val;
            xbf[idx] = f2bf(val);
            if (out) out[idx] = val;
        }
    }
}

extern "C" void kernel_launch(void* const* d_in, const int* in_sizes, int n_in,
                              void* d_out, int out_size, void* d_ws, size_t ws_size,
                              hipStream_t stream) {
    const float* emb   = (const float*)d_in[0];
    const float* pos   = (const float*)d_in[1];
    const float* fw1   = (const float*)d_in[2];
    const float* fb1   = (const float*)d_in[3];
    const float* fw2   = (const float*)d_in[4];
    const float* fb2   = (const float*)d_in[5];
    const float* in2f  = (const float*)d_in[6];
    const float* f2o_w = (const float*)d_in[7];
    const float* f2o_b = (const float*)d_in[8];
    const float* dns_w = (const float*)d_in[9];
    const float* dns_b = (const float*)d_in[10];
    const int*   Z     = (const int*)d_in[11];
    const int*   nbrs  = (const int*)d_in[12];
    const float* mask  = (const float*)d_in[13];

    char* ws = (char*)d_ws;
    size_t off = 0;
    auto alloc = [&](size_t bytes) {
        char* p = ws + off; off += (bytes + 255) & ~(size_t)255; return p;
    };
    float*    x     = (float*)   alloc((size_t)P_ * F_ * 4);
    float*    y     = (float*)   alloc((size_t)P_ * F_ * 4);
    float*    agg4  = (float*)   alloc((size_t)4 * P_ * F_ * 4);   // 8 MB partials
    uint16_t* xbf   = (uint16_t*)alloc((size_t)P_ * F_ * 2);
    uint16_t* w1t   = (uint16_t*)alloc((size_t)L_ * F_ * GP * 2);
    uint16_t* w2t   = (uint16_t*)alloc((size_t)L_ * F_ * F_ * 2);
    uint16_t* in2ft = (uint16_t*)alloc((size_t)L_ * F_ * F_ * 2);
    uint16_t* f2ot  = (uint16_t*)alloc((size_t)L_ * F_ * F_ * 2);
    uint16_t* dnst  = (uint16_t*)alloc((size_t)L_ * F_ * F_ * 2);
    // total scratch: ~13.5 MB

    k_prepw<<<192, 256, 0, stream>>>(fw1, fw2, in2f, f2o_w, dns_w,
                                     w1t, w2t, in2ft, f2ot, dnst);
    k_embed<<<(P_ * F_) / 256, 256, 0, stream>>>(emb, Z, x, xbf);

    for (int l = 0; l < L_; ++l) {
        k_proj<<<P_ / 64, 256, 0, stream>>>(xbf, in2ft + (size_t)l * F_ * F_, y);
        k_layer<<<P_, 256, 0, stream>>>(pos, nbrs, mask, y,
                                        w1t + (size_t)l * F_ * GP, fb1 + (size_t)l * F_,
                                        w2t + (size_t)l * F_ * F_, fb2 + (size_t)l * F_,
                                        agg4);
        k_out_mlp<<<P_ / 64, 256, 0, stream>>>(agg4,
                                               f2ot + (size_t)l * F_ * F_, f2o_b + (size_t)l * F_,
                                               dnst + (size_t)l * F_ * F_, dns_b + (size_t)l * F_,
                                               x, xbf,
                                               (l == L_ - 1) ? (float*)d_out : nullptr);
    }
}

// Round 13
// 181.221 us; speedup vs baseline: 3.4222x; 1.0773x over previous
//
#include <hip/hip_runtime.h>
#include <stdint.h>

#define B_ 16
#define A_ 256
#define N_ 64
#define F_ 128
#define G_ 25
#define GP 32           // G padded to MFMA K=32
#define L_ 3
#define P_ (B_*A_)      // 4096 atoms
#define CUTOFF_ 5.0f
#define OFF0_ 1.2f

typedef float f32x4 __attribute__((ext_vector_type(4)));
typedef __bf16 bf16x8 __attribute__((ext_vector_type(8)));

__device__ __forceinline__ uint16_t f2bf(float f) {
    union { __bf16 b; uint16_t u; } v; v.b = (__bf16)f;  // RNE hw cvt
    return v.u;
}
// shifted softplus: log(1+e^x) - ln2. Fast form; inputs bounded (|x|<~20).
__device__ __forceinline__ float sspf(float x) {
    return fmaf(__log2f(1.0f + __expf(x)), 0.69314718055994531f,
                -0.69314718055994531f);
}

// ---- prep: transpose+pad all GEMM weights to bf16 [f][k] ----
__global__ void k_prepw(const float* __restrict__ fw1, const float* __restrict__ fw2,
                        const float* __restrict__ in2f, const float* __restrict__ f2ow,
                        const float* __restrict__ dnsw,
                        uint16_t* __restrict__ w1t, uint16_t* __restrict__ w2t,
                        uint16_t* __restrict__ in2ft, uint16_t* __restrict__ f2ot,
                        uint16_t* __restrict__ dnst) {
    int t = blockIdx.x * 256 + threadIdx.x;
    if (t < L_ * F_ * GP) {
        int k = t & (GP - 1); int f = (t >> 5) & (F_ - 1); int l = t >> 12;
        float v = (k < G_) ? fw1[(l * G_ + k) * F_ + f] : 0.0f;
        w1t[t] = f2bf(v);
    }
    if (t < L_ * F_ * F_) {
        int k = t & (F_ - 1); int f = (t >> 7) & (F_ - 1); int l = t >> 14;
        const size_t src = (size_t)(l * F_ + k) * F_ + f;
        w2t[t]   = f2bf(fw2[src]);
        in2ft[t] = f2bf(in2f[src]);
        f2ot[t]  = f2bf(f2ow[src]);
        dnst[t]  = f2bf(dnsw[src]);
    }
}

// ---- embedding gather: fp32 x + bf16 shadow ----
__global__ void k_embed(const float* __restrict__ emb, const int* __restrict__ Z,
                        float* __restrict__ x, uint16_t* __restrict__ xbf) {
    int t = blockIdx.x * 256 + threadIdx.x;   // P_*F_ threads
    int p = t >> 7, f = t & 127;
    float v = emb[Z[p] * F_ + f];
    x[t] = v;
    xbf[t] = f2bf(v);
}

// ---- MFMA GEMM: y[4096,128] = xbf @ in2ft^T (bias-free), fp32 out ----
__global__ __launch_bounds__(256) void k_proj(const uint16_t* __restrict__ xbf,
                                              const uint16_t* __restrict__ wt,
                                              float* __restrict__ y) {
    const int wave = threadIdx.x >> 6;
    const int lane = threadIdx.x & 63;
    const int row  = lane & 15;
    const int kg   = lane >> 4;
    const int rb   = blockIdx.x * 64 + wave * 16;

    f32x4 acc[8];
#pragma unroll
    for (int nt = 0; nt < 8; ++nt) acc[nt] = (f32x4){0.f, 0.f, 0.f, 0.f};
#pragma unroll
    for (int ks = 0; ks < 4; ++ks) {
        bf16x8 a = *(const bf16x8*)(xbf + (size_t)(rb + row) * F_ + ks * 32 + kg * 8);
#pragma unroll
        for (int nt = 0; nt < 8; ++nt) {
            bf16x8 bfr = *(const bf16x8*)(wt + (nt * 16 + row) * F_ + ks * 32 + kg * 8);
            acc[nt] = __builtin_amdgcn_mfma_f32_16x16x32_bf16(a, bfr, acc[nt], 0, 0, 0);
        }
    }
#pragma unroll
    for (int nt = 0; nt < 8; ++nt)
#pragma unroll
        for (int j = 0; j < 4; ++j)
            y[(size_t)(rb + kg * 4 + j) * F_ + nt * 16 + row] = acc[nt][j];
}

// ---- fused layer kernel (MFMA): 12 waves = 3 atoms per WG, w2 LDS-staged ----
// WG = 768 thr. Wave w: atom = blk*3 + (w>>2), tile = w&3 (16 edges).
// One barrier after w2 staging, then waves drift. Per-wave h1; cross-tile
// reduction deferred to k_out_mlp via agg4[tile][atom][f]. Biases via MFMA C.
__global__ __launch_bounds__(768) void k_layer(
        const float* __restrict__ pos, const int* __restrict__ nbr,
        const float* __restrict__ mask, const float* __restrict__ y,
        const uint16_t* __restrict__ w1t, const float* __restrict__ b1,
        const uint16_t* __restrict__ w2t, const float* __restrict__ b2,
        float* __restrict__ agg4)
{
    __shared__ uint16_t w2s[F_ * F_];       // 32 KB, swizzled: f*256B + (k2 ^ ((f&7)<<4))
    __shared__ uint16_t h1[12][16 * 128];   // per-wave swizzled H1 tile (4 KiB each)

    // ---- cooperative w2 staging: 2048 16B-vectors over 768 threads ----
    {
        const int t = threadIdx.x;
#pragma unroll
        for (int i = 0; i < 3; ++i) {
            const int idx = i * 768 + t;
            if (idx < 2048) {
                const int f2 = idx >> 4, kc2 = (idx & 15) * 8;
                uint4 v2 = *(const uint4*)(w2t + f2 * F_ + kc2);
                *(uint4*)((char*)w2s + f2 * 256 + ((kc2 * 2) ^ ((f2 & 7) << 4))) = v2;
            }
        }
    }
    __syncthreads();

    const int wave = threadIdx.x >> 6;
    const int lane = threadIdx.x & 63;
    const int row  = lane & 15;
    const int kg   = lane >> 4;
    const int atom = blockIdx.x * 3 + (wave >> 2);
    if (atom >= P_) return;                 // tail guard (after barrier)
    const int tile = wave & 3;
    const int molbase = atom & ~(A_ - 1);

    const float px = pos[atom * 3 + 0];
    const float py = pos[atom * 3 + 1];
    const float pz = pos[atom * 3 + 2];

    const int e_mine = atom * N_ + tile * 16 + row;
    const int jrow_mine = molbase + nbr[e_mine];
    const float dx = pos[jrow_mine * 3 + 0] - px;
    const float dy = pos[jrow_mine * 3 + 1] - py;
    const float dz = pos[jrow_mine * 3 + 2] - pz;
    const float r = sqrtf(dx * dx + dy * dy + dz * dz + 1e-9f);
    const float fcr = (r <= CUTOFF_) ? mask[e_mine] : 0.0f;
    const float step = 3.8f / 24.0f;
    const float coef = -0.5f / (step * step);
    bf16x8 a1v;
#pragma unroll
    for (int j = 0; j < 8; ++j) {
        const int k = kg * 8 + j;
        float val = 0.0f;
        if (k < G_) { const float d = r - (OFF0_ + step * (float)k); val = __expf(coef * d * d); }
        a1v[j] = (__bf16)val;
    }

    uint16_t* hl = h1[wave];

    // GEMM1: [16,32]@[32,128], B from global (cache-hot), bias in C,
    // ssp -> XOR-swizzled per-wave h1
#pragma unroll
    for (int nt = 0; nt < 8; ++nt) {
        const float b1v = b1[nt * 16 + row];
        const f32x4 c1 = {b1v, b1v, b1v, b1v};
        bf16x8 bfr = *(const bf16x8*)(w1t + (nt * 16 + row) * GP + kg * 8);
        f32x4 acc1 = __builtin_amdgcn_mfma_f32_16x16x32_bf16(a1v, bfr, c1, 0, 0, 0);
        const int col = nt * 16 + row;
#pragma unroll
        for (int j = 0; j < 4; ++j) {
            const int rr = kg * 4 + j;
            const int byt = rr * 256 + ((col * 2) ^ ((rr & 7) << 4));
            *(uint16_t*)((char*)hl + byt) = f2bf(sspf(acc1[j]));
        }
    }
    // same-wave LDS write->read; compiler inserts lgkmcnt waits (no barrier)

    // GEMM2: [16,128]@[128,128], K=128 in 4 steps, B from LDS, bias in C
    f32x4 acc2[8];
#pragma unroll
    for (int nt = 0; nt < 8; ++nt) {
        const float b2v = b2[nt * 16 + row];
        acc2[nt] = (f32x4){b2v, b2v, b2v, b2v};
    }
#pragma unroll
    for (int ks = 0; ks < 4; ++ks) {
        const int kbyte = ks * 64 + kg * 16;
        bf16x8 a2 = *(const bf16x8*)((char*)hl + row * 256 + (kbyte ^ ((row & 7) << 4)));
#pragma unroll
        for (int nt = 0; nt < 8; ++nt) {
            bf16x8 bfr = *(const bf16x8*)((char*)w2s + (nt * 16 + row) * 256 +
                                          (kbyte ^ ((row & 7) << 4)));
            acc2[nt] = __builtin_amdgcn_mfma_f32_16x16x32_bf16(a2, bfr, acc2[nt], 0, 0, 0);
        }
    }

    // fused epilogue: W = acc2*fcut, modulate by gathered y, accumulate
    float fc[4]; int jr[4];
#pragma unroll
    for (int j = 0; j < 4; ++j) {
        fc[j] = __shfl(fcr, kg * 4 + j);
        jr[j] = __shfl(jrow_mine, kg * 4 + j);
    }
    float pacc[8];
#pragma unroll
    for (int nt = 0; nt < 8; ++nt) {
        const int col = nt * 16 + row;
        float s = 0.0f;
#pragma unroll
        for (int j = 0; j < 4; ++j) {
            s += (acc2[nt][j] * fc[j]) * y[jr[j] * F_ + col];
        }
        s += __shfl_xor(s, 16);
        s += __shfl_xor(s, 32);
        pacc[nt] = s;
    }
    if (kg == 0) {
#pragma unroll
        for (int nt = 0; nt < 8; ++nt)
            agg4[((size_t)tile * P_ + atom) * F_ + nt * 16 + row] = pacc[nt];
    }
}

// ---- atom MLP (MFMA): x += ssp(sum4(agg4)@f2o + ba) @ dns + bb ----
__global__ __launch_bounds__(256) void k_out_mlp(
        const float* __restrict__ agg4,
        const uint16_t* __restrict__ f2ot, const float* __restrict__ ba,
        const uint16_t* __restrict__ dnst, const float* __restrict__ bb,
        float* __restrict__ x, uint16_t* __restrict__ xbf,
        float* __restrict__ out)
{
    __shared__ uint16_t hs[4][16 * 128];
    const int wave = threadIdx.x >> 6;
    const int lane = threadIdx.x & 63;
    const int row  = lane & 15;
    const int kg   = lane >> 4;
    const int rb   = blockIdx.x * 64 + wave * 16;
    uint16_t* hl = hs[wave];

    f32x4 acc[8];
#pragma unroll
    for (int nt = 0; nt < 8; ++nt) {
        const float bav = ba[nt * 16 + row];
        acc[nt] = (f32x4){bav, bav, bav, bav};
    }
#pragma unroll
    for (int ks = 0; ks < 4; ++ks) {
        const size_t base = (size_t)(rb + row) * F_ + ks * 32 + kg * 8;
        float4 u0 = *(const float4*)(agg4 + base);
        float4 u1 = *(const float4*)(agg4 + base + 4);
#pragma unroll
        for (int p = 1; p < 4; ++p) {
            const size_t pb = (size_t)p * P_ * F_ + base;
            float4 v0 = *(const float4*)(agg4 + pb);
            float4 v1 = *(const float4*)(agg4 + pb + 4);
            u0.x += v0.x; u0.y += v0.y; u0.z += v0.z; u0.w += v0.w;
            u1.x += v1.x; u1.y += v1.y; u1.z += v1.z; u1.w += v1.w;
        }
        bf16x8 a;
        a[0] = (__bf16)u0.x; a[1] = (__bf16)u0.y; a[2] = (__bf16)u0.z; a[3] = (__bf16)u0.w;
        a[4] = (__bf16)u1.x; a[5] = (__bf16)u1.y; a[6] = (__bf16)u1.z; a[7] = (__bf16)u1.w;
#pragma unroll
        for (int nt = 0; nt < 8; ++nt) {
            bf16x8 bfr = *(const bf16x8*)(f2ot + (nt * 16 + row) * F_ + ks * 32 + kg * 8);
            acc[nt] = __builtin_amdgcn_mfma_f32_16x16x32_bf16(a, bfr, acc[nt], 0, 0, 0);
        }
    }
#pragma unroll
    for (int nt = 0; nt < 8; ++nt) {
        const int col = nt * 16 + row;
#pragma unroll
        for (int j = 0; j < 4; ++j) {
            const int rr = kg * 4 + j;
            const int byt = rr * 256 + ((col * 2) ^ ((rr & 7) << 4));
            *(uint16_t*)((char*)hl + byt) = f2bf(sspf(acc[nt][j]));
        }
    }
    // same-wave LDS write->read (no barrier)

    f32x4 acc2[8];
#pragma unroll
    for (int nt = 0; nt < 8; ++nt) {
        const float bbv = bb[nt * 16 + row];
        acc2[nt] = (f32x4){bbv, bbv, bbv, bbv};
    }
#pragma unroll
    for (int ks = 0; ks < 4; ++ks) {
        const int kbyte = ks * 64 + kg * 16;
        bf16x8 a2 = *(const bf16x8*)((char*)hl + row * 256 + (kbyte ^ ((row & 7) << 4)));
#pragma unroll
        for (int nt = 0; nt < 8; ++nt) {
            bf16x8 bfr = *(const bf16x8*)(dnst + (nt * 16 + row) * F_ + ks * 32 + kg * 8);
            acc2[nt] = __builtin_amdgcn_mfma_f32_16x16x32_bf16(a2, bfr, acc2[nt], 0, 0, 0);
        }
    }
#pragma unroll
    for (int nt = 0; nt < 8; ++nt) {
#pragma unroll
        for (int j = 0; j < 4; ++j) {
            const size_t idx = (size_t)(rb + kg * 4 + j) * F_ + nt * 16 + row;
            const float val = acc2[nt][j] + x[idx];
            x[idx] = val;
            xbf[idx] = f2bf(val);
            if (out) out[idx] = val;
        }
    }
}

extern "C" void kernel_launch(void* const* d_in, const int* in_sizes, int n_in,
                              void* d_out, int out_size, void* d_ws, size_t ws_size,
                              hipStream_t stream) {
    const float* emb   = (const float*)d_in[0];
    const float* pos   = (const float*)d_in[1];
    const float* fw1   = (const float*)d_in[2];
    const float* fb1   = (const float*)d_in[3];
    const float* fw2   = (const float*)d_in[4];
    const float* fb2   = (const float*)d_in[5];
    const float* in2f  = (const float*)d_in[6];
    const float* f2o_w = (const float*)d_in[7];
    const float* f2o_b = (const float*)d_in[8];
    const float* dns_w = (const float*)d_in[9];
    const float* dns_b = (const float*)d_in[10];
    const int*   Z     = (const int*)d_in[11];
    const int*   nbrs  = (const int*)d_in[12];
    const float* mask  = (const float*)d_in[13];

    char* ws = (char*)d_ws;
    size_t off = 0;
    auto alloc = [&](size_t bytes) {
        char* p = ws + off; off += (bytes + 255) & ~(size_t)255; return p;
    };
    float*    x     = (float*)   alloc((size_t)P_ * F_ * 4);
    float*    y     = (float*)   alloc((size_t)P_ * F_ * 4);
    float*    agg4  = (float*)   alloc((size_t)4 * P_ * F_ * 4);   // 8 MB partials
    uint16_t* xbf   = (uint16_t*)alloc((size_t)P_ * F_ * 2);
    uint16_t* w1t   = (uint16_t*)alloc((size_t)L_ * F_ * GP * 2);
    uint16_t* w2t   = (uint16_t*)alloc((size_t)L_ * F_ * F_ * 2);
    uint16_t* in2ft = (uint16_t*)alloc((size_t)L_ * F_ * F_ * 2);
    uint16_t* f2ot  = (uint16_t*)alloc((size_t)L_ * F_ * F_ * 2);
    uint16_t* dnst  = (uint16_t*)alloc((size_t)L_ * F_ * F_ * 2);
    // total scratch: ~13.5 MB

    k_prepw<<<192, 256, 0, stream>>>(fw1, fw2, in2f, f2o_w, dns_w,
                                     w1t, w2t, in2ft, f2ot, dnst);
    k_embed<<<(P_ * F_) / 256, 256, 0, stream>>>(emb, Z, x, xbf);

    const int nwg_layer = (P_ + 2) / 3;   // 1366
    for (int l = 0; l < L_; ++l) {
        k_proj<<<P_ / 64, 256, 0, stream>>>(xbf, in2ft + (size_t)l * F_ * F_, y);
        k_layer<<<nwg_layer, 768, 0, stream>>>(pos, nbrs, mask, y,
                                               w1t + (size_t)l * F_ * GP, fb1 + (size_t)l * F_,
                                               w2t + (size_t)l * F_ * F_, fb2 + (size_t)l * F_,
                                               agg4);
        k_out_mlp<<<P_ / 64, 256, 0, stream>>>(agg4,
                                               f2ot + (size_t)l * F_ * F_, f2o_b + (size_t)l * F_,
                                               dnst + (size_t)l * F_ * F_, dns_b + (size_t)l * F_,
                                               x, xbf,
                                               (l == L_ - 1) ? (float*)d_out : nullptr);
    }
}

// Round 14
// 159.400 us; speedup vs baseline: 3.8907x; 1.1369x over previous
//
#include <hip/hip_runtime.h>
#include <stdint.h>

#define B_ 16
#define A_ 256
#define N_ 64
#define F_ 128
#define G_ 25
#define GP 32           // G padded to MFMA K=32
#define L_ 3
#define P_ (B_*A_)      // 4096 atoms
#define CUTOFF_ 5.0f
#define OFF0_ 1.2f

typedef float f32x4 __attribute__((ext_vector_type(4)));
typedef __bf16 bf16x8 __attribute__((ext_vector_type(8)));

__device__ __forceinline__ uint16_t f2bf(float f) {
    union { __bf16 b; uint16_t u; } v; v.b = (__bf16)f;  // RNE hw cvt
    return v.u;
}
// shifted softplus: log(1+e^x) - ln2. Fast form; inputs bounded (|x|<~20).
__device__ __forceinline__ float sspf(float x) {
    return fmaf(__log2f(1.0f + __expf(x)), 0.69314718055994531f,
                -0.69314718055994531f);
}

// ---- prep: transpose+pad all GEMM weights to bf16 [f][k] ----
__global__ void k_prepw(const float* __restrict__ fw1, const float* __restrict__ fw2,
                        const float* __restrict__ in2f, const float* __restrict__ f2ow,
                        const float* __restrict__ dnsw,
                        uint16_t* __restrict__ w1t, uint16_t* __restrict__ w2t,
                        uint16_t* __restrict__ in2ft, uint16_t* __restrict__ f2ot,
                        uint16_t* __restrict__ dnst) {
    int t = blockIdx.x * 256 + threadIdx.x;
    if (t < L_ * F_ * GP) {
        int k = t & (GP - 1); int f = (t >> 5) & (F_ - 1); int l = t >> 12;
        float v = (k < G_) ? fw1[(l * G_ + k) * F_ + f] : 0.0f;
        w1t[t] = f2bf(v);
    }
    if (t < L_ * F_ * F_) {
        int k = t & (F_ - 1); int f = (t >> 7) & (F_ - 1); int l = t >> 14;
        const size_t src = (size_t)(l * F_ + k) * F_ + f;
        w2t[t]   = f2bf(fw2[src]);
        in2ft[t] = f2bf(in2f[src]);
        f2ot[t]  = f2bf(f2ow[src]);
        dnst[t]  = f2bf(dnsw[src]);
    }
}

// ---- embed + first projection: x = emb[Z]; y0 = x @ in2f[0]^T (MFMA) ----
__global__ __launch_bounds__(256) void k_embed_proj(
        const float* __restrict__ emb, const int* __restrict__ Z,
        const uint16_t* __restrict__ in2ft0,
        float* __restrict__ x, float* __restrict__ y)
{
    const int wave = threadIdx.x >> 6;
    const int lane = threadIdx.x & 63;
    const int row  = lane & 15;
    const int kg   = lane >> 4;
    const int rb   = blockIdx.x * 64 + wave * 16;
    const int zr   = Z[rb + row];

    f32x4 acc[8];
#pragma unroll
    for (int nt = 0; nt < 8; ++nt) acc[nt] = (f32x4){0.f, 0.f, 0.f, 0.f};
#pragma unroll
    for (int ks = 0; ks < 4; ++ks) {
        const float* ep = emb + (size_t)zr * F_ + ks * 32 + kg * 8;
        float4 e0 = *(const float4*)ep;
        float4 e1 = *(const float4*)(ep + 4);
        bf16x8 a;
        a[0] = (__bf16)e0.x; a[1] = (__bf16)e0.y; a[2] = (__bf16)e0.z; a[3] = (__bf16)e0.w;
        a[4] = (__bf16)e1.x; a[5] = (__bf16)e1.y; a[6] = (__bf16)e1.z; a[7] = (__bf16)e1.w;
#pragma unroll
        for (int nt = 0; nt < 8; ++nt) {
            bf16x8 bfr = *(const bf16x8*)(in2ft0 + (nt * 16 + row) * F_ + ks * 32 + kg * 8);
            acc[nt] = __builtin_amdgcn_mfma_f32_16x16x32_bf16(a, bfr, acc[nt], 0, 0, 0);
        }
    }
#pragma unroll
    for (int nt = 0; nt < 8; ++nt)
#pragma unroll
        for (int j = 0; j < 4; ++j)
            y[(size_t)(rb + kg * 4 + j) * F_ + nt * 16 + row] = acc[nt][j];

    // coalesced x write (embedding gather, L1-hot after A-frag loads)
    const int rb0 = blockIdx.x * 64;
#pragma unroll
    for (int i = 0; i < 32; ++i) {
        int idx = i * 256 + threadIdx.x;      // 0..8191
        int p = rb0 + (idx >> 7), f = idx & 127;
        x[(size_t)p * F_ + f] = emb[(size_t)Z[p] * F_ + f];
    }
}

// ---- fully fused layer: CFConv + atom MLP + next-layer projection ----
// WG = 768 thr = 12 waves = 3 atoms. Phase2 (per-wave edge tile, barrier-free)
// -> psum in LDS -> col-split MLP tail on waves 0..7 (nt = wave).
__global__ __launch_bounds__(768) void k_layer_full(
        const float* __restrict__ pos, const int* __restrict__ nbr,
        const float* __restrict__ mask, const float* __restrict__ y,
        const uint16_t* __restrict__ w1t, const float* __restrict__ b1,
        const uint16_t* __restrict__ w2t, const float* __restrict__ b2,
        const uint16_t* __restrict__ f2ot, const float* __restrict__ ba,
        const uint16_t* __restrict__ dnst, const float* __restrict__ bb,
        const uint16_t* __restrict__ in2ftN,   // next-layer proj weights or null
        float* __restrict__ x, float* __restrict__ yout, float* __restrict__ out)
{
    __shared__ uint16_t w2s[F_ * F_];             // 32 KB swizzled
    __shared__ __align__(16) unsigned char ar[12 * 4096];  // h1 / psum / mlp arena

    // ---- cooperative w2 staging ----
    {
        const int t = threadIdx.x;
#pragma unroll
        for (int i = 0; i < 3; ++i) {
            const int idx = i * 768 + t;
            if (idx < 2048) {
                const int f2 = idx >> 4, kc2 = (idx & 15) * 8;
                uint4 v2 = *(const uint4*)(w2t + f2 * F_ + kc2);
                *(uint4*)((char*)w2s + f2 * 256 + ((kc2 * 2) ^ ((f2 & 7) << 4))) = v2;
            }
        }
    }
    __syncthreads();   // barrier 1

    const int wave = threadIdx.x >> 6;
    const int lane = threadIdx.x & 63;
    const int row  = lane & 15;
    const int kg   = lane >> 4;
    const int a0   = blockIdx.x * 3;
    const int valid = (P_ - a0 < 3) ? (P_ - a0) : 3;
    const int aidx = wave >> 2;            // atom within WG (0..2)
    const int atom = a0 + aidx;
    const int tile = wave & 3;

    uint16_t* hl = (uint16_t*)(ar + wave * 4096);

    if (aidx < valid) {
        const int molbase = atom & ~(A_ - 1);
        const float px = pos[atom * 3 + 0];
        const float py = pos[atom * 3 + 1];
        const float pz = pos[atom * 3 + 2];

        const int e_mine = atom * N_ + tile * 16 + row;
        const int jrow_mine = molbase + nbr[e_mine];
        const float dx = pos[jrow_mine * 3 + 0] - px;
        const float dy = pos[jrow_mine * 3 + 1] - py;
        const float dz = pos[jrow_mine * 3 + 2] - pz;
        const float r = sqrtf(dx * dx + dy * dy + dz * dz + 1e-9f);
        const float fcr = (r <= CUTOFF_) ? mask[e_mine] : 0.0f;
        const float step = 3.8f / 24.0f;
        const float coef = -0.5f / (step * step);
        bf16x8 a1v;
#pragma unroll
        for (int j = 0; j < 8; ++j) {
            const int k = kg * 8 + j;
            float val = 0.0f;
            if (k < G_) { const float d = r - (OFF0_ + step * (float)k); val = __expf(coef * d * d); }
            a1v[j] = (__bf16)val;
        }

        // GEMM1 -> ssp -> swizzled per-wave h1
#pragma unroll
        for (int nt = 0; nt < 8; ++nt) {
            const float b1v = b1[nt * 16 + row];
            const f32x4 c1 = {b1v, b1v, b1v, b1v};
            bf16x8 bfr = *(const bf16x8*)(w1t + (nt * 16 + row) * GP + kg * 8);
            f32x4 acc1 = __builtin_amdgcn_mfma_f32_16x16x32_bf16(a1v, bfr, c1, 0, 0, 0);
            const int col = nt * 16 + row;
#pragma unroll
            for (int j = 0; j < 4; ++j) {
                const int rr = kg * 4 + j;
                const int byt = rr * 256 + ((col * 2) ^ ((rr & 7) << 4));
                *(uint16_t*)((char*)hl + byt) = f2bf(sspf(acc1[j]));
            }
        }

        // GEMM2 (B from w2s)
        f32x4 acc2[8];
#pragma unroll
        for (int nt = 0; nt < 8; ++nt) {
            const float b2v = b2[nt * 16 + row];
            acc2[nt] = (f32x4){b2v, b2v, b2v, b2v};
        }
#pragma unroll
        for (int ks = 0; ks < 4; ++ks) {
            const int kbyte = ks * 64 + kg * 16;
            bf16x8 a2 = *(const bf16x8*)((char*)hl + row * 256 + (kbyte ^ ((row & 7) << 4)));
#pragma unroll
            for (int nt = 0; nt < 8; ++nt) {
                bf16x8 bfr = *(const bf16x8*)((char*)w2s + (nt * 16 + row) * 256 +
                                              (kbyte ^ ((row & 7) << 4)));
                acc2[nt] = __builtin_amdgcn_mfma_f32_16x16x32_bf16(a2, bfr, acc2[nt], 0, 0, 0);
            }
        }

        // epilogue: mask, y-gather modulate, cross-kg reduce -> psum (own h1)
        float fc[4]; int jr[4];
#pragma unroll
        for (int j = 0; j < 4; ++j) {
            fc[j] = __shfl(fcr, kg * 4 + j);
            jr[j] = __shfl(jrow_mine, kg * 4 + j);
        }
        float* psum = (float*)hl;   // h1 rows already consumed
#pragma unroll
        for (int nt = 0; nt < 8; ++nt) {
            const int col = nt * 16 + row;
            float s = 0.0f;
#pragma unroll
            for (int j = 0; j < 4; ++j)
                s += (acc2[nt][j] * fc[j]) * y[jr[j] * F_ + col];
            s += __shfl_xor(s, 16);
            s += __shfl_xor(s, 32);
            if (kg == 0) psum[col] = s;
        }
    }
    __syncthreads();   // barrier 2: all psum written, h1 dead

    // ---- pre-sum 4 tiles -> bf16 abf[4][128] at ar+2048 ----
    {
        const int t = threadIdx.x;
        if (t < 384) {
            const int a = t >> 7, f = t & 127;
            float s = 0.f;
#pragma unroll
            for (int tt = 0; tt < 4; ++tt)
                s += ((const float*)(ar + (a * 4 + tt) * 4096))[f];
            ((uint16_t*)(ar + 2048))[a * 128 + f] = f2bf(s);
        }
    }
    __syncthreads();   // barrier 3

    const uint16_t* abf = (const uint16_t*)(ar + 2048);
    uint16_t* mlpH = (uint16_t*)(ar + 4096);
    float*    mlpX = (float*)(ar + 8192);
    const int fcol = wave * 16 + row;      // this wave's output column
    const int rcl  = (row < 3) ? row : 3;  // clamped A-row (atom) index

    // GEMM_a: H = ssp(abf @ f2o + ba)  (waves 0..7, col tile nt = wave)
    if (wave < 8) {
        const float bav = ba[fcol];
        f32x4 acc = {bav, bav, bav, bav};
#pragma unroll
        for (int ks = 0; ks < 4; ++ks) {
            bf16x8 a = *(const bf16x8*)(abf + rcl * 128 + ks * 32 + kg * 8);
            bf16x8 bfr = *(const bf16x8*)(f2ot + fcol * F_ + ks * 32 + kg * 8);
            acc = __builtin_amdgcn_mfma_f32_16x16x32_bf16(a, bfr, acc, 0, 0, 0);
        }
#pragma unroll
        for (int j = 0; j < 4; ++j) {
            const int rr = kg * 4 + j;
            const int byt = rr * 256 + ((fcol * 2) ^ ((rr & 7) << 4));
            *(uint16_t*)((char*)mlpH + byt) = f2bf(sspf(acc[j]));
        }
    }
    __syncthreads();   // barrier 4

    // GEMM_b: x_new = H @ dns + bb + x  (waves 0..7)
    if (wave < 8) {
        const float bbv = bb[fcol];
        f32x4 acc = {bbv, bbv, bbv, bbv};
#pragma unroll
        for (int ks = 0; ks < 4; ++ks) {
            const int kbyte = ks * 64 + kg * 16;
            bf16x8 a2 = *(const bf16x8*)((char*)mlpH + row * 256 + (kbyte ^ ((row & 7) << 4)));
            bf16x8 bfr = *(const bf16x8*)(dnst + fcol * F_ + ks * 32 + kg * 8);
            acc = __builtin_amdgcn_mfma_f32_16x16x32_bf16(a2, bfr, acc, 0, 0, 0);
        }
        if (kg == 0) {
#pragma unroll
            for (int j = 0; j < 3; ++j) {
                if (j < valid) {
                    const size_t idx = (size_t)(a0 + j) * F_ + fcol;
                    const float val = acc[j] + x[idx];
                    x[idx] = val;
                    mlpX[j * 128 + fcol] = val;
                    if (out) out[idx] = val;
                }
            }
        }
    }

    // GEMM_c: y_next = x_new @ in2f[l+1]  (waves 0..7)
    if (in2ftN) {
        __syncthreads();   // barrier 5 (uniform branch)
        if (wave < 8) {
            f32x4 acc = {0.f, 0.f, 0.f, 0.f};
#pragma unroll
            for (int ks = 0; ks < 4; ++ks) {
                const float* xp = mlpX + rcl * 128 + ks * 32 + kg * 8;
                float4 u0 = *(const float4*)xp;
                float4 u1 = *(const float4*)(xp + 4);
                bf16x8 a;
                a[0] = (__bf16)u0.x; a[1] = (__bf16)u0.y; a[2] = (__bf16)u0.z; a[3] = (__bf16)u0.w;
                a[4] = (__bf16)u1.x; a[5] = (__bf16)u1.y; a[6] = (__bf16)u1.z; a[7] = (__bf16)u1.w;
                bf16x8 bfr = *(const bf16x8*)(in2ftN + fcol * F_ + ks * 32 + kg * 8);
                acc = __builtin_amdgcn_mfma_f32_16x16x32_bf16(a, bfr, acc, 0, 0, 0);
            }
            if (kg == 0) {
#pragma unroll
                for (int j = 0; j < 3; ++j)
                    if (j < valid)
                        yout[(size_t)(a0 + j) * F_ + fcol] = acc[j];
            }
        }
    }
}

extern "C" void kernel_launch(void* const* d_in, const int* in_sizes, int n_in,
                              void* d_out, int out_size, void* d_ws, size_t ws_size,
                              hipStream_t stream) {
    const float* emb   = (const float*)d_in[0];
    const float* pos   = (const float*)d_in[1];
    const float* fw1   = (const float*)d_in[2];
    const float* fb1   = (const float*)d_in[3];
    const float* fw2   = (const float*)d_in[4];
    const float* fb2   = (const float*)d_in[5];
    const float* in2f  = (const float*)d_in[6];
    const float* f2o_w = (const float*)d_in[7];
    const float* f2o_b = (const float*)d_in[8];
    const float* dns_w = (const float*)d_in[9];
    const float* dns_b = (const float*)d_in[10];
    const int*   Z     = (const int*)d_in[11];
    const int*   nbrs  = (const int*)d_in[12];
    const float* mask  = (const float*)d_in[13];

    char* ws = (char*)d_ws;
    size_t off = 0;
    auto alloc = [&](size_t bytes) {
        char* p = ws + off; off += (bytes + 255) & ~(size_t)255; return p;
    };
    float*    x     = (float*)   alloc((size_t)P_ * F_ * 4);
    float*    y0    = (float*)   alloc((size_t)P_ * F_ * 4);
    float*    y1    = (float*)   alloc((size_t)P_ * F_ * 4);
    uint16_t* w1t   = (uint16_t*)alloc((size_t)L_ * F_ * GP * 2);
    uint16_t* w2t   = (uint16_t*)alloc((size_t)L_ * F_ * F_ * 2);
    uint16_t* in2ft = (uint16_t*)alloc((size_t)L_ * F_ * F_ * 2);
    uint16_t* f2ot  = (uint16_t*)alloc((size_t)L_ * F_ * F_ * 2);
    uint16_t* dnst  = (uint16_t*)alloc((size_t)L_ * F_ * F_ * 2);
    // total scratch: ~6.8 MB

    k_prepw<<<192, 256, 0, stream>>>(fw1, fw2, in2f, f2o_w, dns_w,
                                     w1t, w2t, in2ft, f2ot, dnst);
    k_embed_proj<<<P_ / 64, 256, 0, stream>>>(emb, Z, in2ft, x, y0);

    const int nwg = (P_ + 2) / 3;   // 1366
    float* ycur = y0;
    float* ynxt = y1;
    for (int l = 0; l < L_; ++l) {
        k_layer_full<<<nwg, 768, 0, stream>>>(
            pos, nbrs, mask, ycur,
            w1t + (size_t)l * F_ * GP, fb1 + (size_t)l * F_,
            w2t + (size_t)l * F_ * F_, fb2 + (size_t)l * F_,
            f2ot + (size_t)l * F_ * F_, f2o_b + (size_t)l * F_,
            dnst + (size_t)l * F_ * F_, dns_b + (size_t)l * F_,
            (l < L_ - 1) ? (in2ft + (size_t)(l + 1) * F_ * F_) : nullptr,
            x, ynxt, (l == L_ - 1) ? (float*)d_out : nullptr);
        float* t = ycur; ycur = ynxt; ynxt = t;
    }
}